// Round 2
// baseline (496.652 us; speedup 1.0000x reference)
//
#include <hip/hip_runtime.h>
#include <hip/hip_fp16.h>

#define N_NODES 100000
#define N_EDGES 1000000
#define N_GRAPHS 1000
#define EMBED 64
#define OUT_DIM 128
#define BN_EPS 1e-5f
#define NBINS 782                          // dst>>7 -> 128 nodes per bin
#define NSCB 512                           // scatter blocks (fixed edge ranges)
#define EPB ((N_EDGES + NSCB - 1) / NSCB)  // 1954 edges per block
#define NTILES (N_NODES / 16)              // 6250 exact

#define GB_BLOCKS 512                      // fused gemm grid: 2 blocks/CU guaranteed resident
#define GB_WAVES (GB_BLOCKS * 4)           // 2048 waves
#define TPW 4                              // ceil(6250/2048) tiles per wave

typedef _Float16 half8 __attribute__((ext_vector_type(8)));
typedef float floatx4 __attribute__((ext_vector_type(4)));

// Software grid barrier (graph-capture-safe, unlike hipLaunchCooperativeKernel).
// Requires all blocks co-resident: GB_BLOCKS=512 at __launch_bounds__(256,2) = 2 blocks/CU
// across 256 CUs, ~3KB LDS — residency guaranteed with wide margin.
// __syncthreads() drains vmcnt(0) (compiler-enforced) so the block's device-scope
// atomicAdds are at the coherent point before the counter bump. Bounded spin as a
// fail-visible (not hang) safety net.
__device__ __forceinline__ void grid_barrier(int* bar, int target) {
    __syncthreads();
    if (threadIdx.x == 0) {
        __threadfence();
        atomicAdd(bar, 1);
        int spins = 0;
        while (__hip_atomic_load(bar, __ATOMIC_ACQUIRE, __HIP_MEMORY_SCOPE_AGENT) < target) {
            __builtin_amdgcn_s_sleep(8);
            if (++spins > (1 << 22)) break;   // ~1s failsafe: wrong answer beats deadlock
        }
    }
    __syncthreads();
}

// ---------------- one-time structure kernels ----------------

// writes fp32 h and fp16 mirror; builds graph boundaries; zeroes gsum
__global__ void embed_kernel(const int* __restrict__ nfeat,
                             const float* __restrict__ atom_embed,
                             float4* __restrict__ h4,
                             __half* __restrict__ hh,
                             const int* __restrict__ gid,
                             int* __restrict__ gstart,
                             float* __restrict__ gsum) {
    int idx = blockIdx.x * blockDim.x + threadIdx.x;   // one float4 each
    if (idx <= N_NODES) {   // folded gbound
        int cur  = (idx < N_NODES) ? gid[idx] : N_GRAPHS;
        int prev = (idx == 0) ? -1 : gid[idx - 1];
        for (int g = prev + 1; g <= cur; ++g) gstart[g] = idx;
    }
    if (idx < N_GRAPHS * EMBED) gsum[idx] = 0.0f;
    if (idx >= N_NODES * 16) return;
    int v = idx >> 4, q = idx & 15;
    const float4* ae = (const float4*)atom_embed;
    float4 val = ae[nfeat[v] * 16 + q];
    h4[idx] = val;
    __half2 m0 = __floats2half2_rn(val.x, val.y);
    __half2 m1 = __floats2half2_rn(val.z, val.w);
    uint2 packed;
    packed.x = *(unsigned*)&m0;
    packed.y = *(unsigned*)&m1;
    ((uint2*)hh)[idx] = packed;
}

// per-block LDS histogram of its fixed edge range -> blockhist[bin][block]
__global__ void hist2_kernel(const int* __restrict__ dst, int* __restrict__ blockhist) {
    __shared__ int hist[NBINS];
    for (int i = threadIdx.x; i < NBINS; i += 256) hist[i] = 0;
    __syncthreads();
    int b = blockIdx.x;
    int e0 = b * EPB, e1 = min(e0 + EPB, N_EDGES);
    for (int e = e0 + threadIdx.x; e < e1; e += 256)
        atomicAdd(&hist[dst[e] >> 7], 1);
    __syncthreads();
    for (int i = threadIdx.x; i < NBINS; i += 256)
        blockhist[i * NSCB + b] = hist[i];
}

// one block per bin: exclusive scan of its 512 block-counts -> gofs; total per bin
__global__ void binreduce_kernel(const int* __restrict__ blockhist,
                                 int* __restrict__ gofs, int* __restrict__ total) {
    __shared__ int sm[NSCB];
    int bin = blockIdx.x;
    int i = threadIdx.x;   // 0..511
    int orig = blockhist[bin * NSCB + i];
    sm[i] = orig;
    __syncthreads();
    for (int off = 1; off < NSCB; off <<= 1) {
        int val = sm[i];
        if (i >= off) val += sm[i - off];
        __syncthreads();
        sm[i] = val;
        __syncthreads();
    }
    gofs[bin * NSCB + i] = sm[i] - orig;   // exclusive within bin
    if (i == NSCB - 1) total[bin] = sm[i];
}

// scan 782 bin totals -> binoff (exclusive); zeroes BN stats + barrier counters; packs W frags
__global__ void binscan_kernel(const int* __restrict__ total,
                               int* __restrict__ binoff, float* __restrict__ stats,
                               int* __restrict__ bar,
                               const float* __restrict__ conv_W,
                               _Float16* __restrict__ wfrag) {
    __shared__ int sm[1024];
    int i = threadIdx.x;
    if (i < 6 * EMBED) stats[i] = 0.0f;
    if (i < 8) bar[i] = 0;
    // folded wpack: 3 layers x 512 slots
    for (int s = i; s < 3 * 512; s += 1024) {
        int L = s >> 9, slot = s & 511;
        int lane = slot & 63;
        int f = slot >> 6;          // nt*2+kh
        int nt = f >> 1, kh = f & 1;
        int n  = nt * 16 + (lane & 15);
        int k0 = kh * 32 + (lane >> 4) * 8;
        const float* W = conv_W + L * 4096;
        _Float16* out = wfrag + L * 4096;
#pragma unroll
        for (int j = 0; j < 8; ++j)
            out[slot * 8 + j] = (_Float16)W[(k0 + j) * 64 + n];
    }
    int orig = (i < NBINS) ? total[i] : 0;
    sm[i] = orig;
    __syncthreads();
    for (int off = 1; off < 1024; off <<= 1) {
        int val = sm[i];
        if (i >= off) val += sm[i - off];
        __syncthreads();
        sm[i] = val;
        __syncthreads();
    }
    if (i < NBINS) binoff[i] = sm[i] - orig;
    if (i == 0) binoff[NBINS] = N_EDGES;
}

// deterministic multisplit scatter: LDS cursors seeded from binoff+gofs.
__global__ void binscatter_kernel(const int* __restrict__ src, const int* __restrict__ dst,
                                  const int* __restrict__ efeat,
                                  const int* __restrict__ binoff, const int* __restrict__ gofs,
                                  unsigned* __restrict__ binned) {
    __shared__ int cur[NBINS];
    int b = blockIdx.x;
    for (int i = threadIdx.x; i < NBINS; i += 256)
        cur[i] = binoff[i] + gofs[i * NSCB + b];
    __syncthreads();
    int e0 = b * EPB, e1 = min(e0 + EPB, N_EDGES);
    for (int e = e0 + threadIdx.x; e < e1; e += 256) {
        int t = dst[e];
        int bin = t >> 7;
        int pos = atomicAdd(&cur[bin], 1);   // LDS atomic
        binned[pos] = (unsigned)src[e] | ((unsigned)efeat[e] << 17)
                    | ((unsigned)(t & 127) << 20);
    }
}

// one block per bin: local deg count + local scan -> rowptr slice + ebuf region
__global__ void bincsr_kernel(const unsigned* __restrict__ binned,
                              const int* __restrict__ binoff,
                              int* __restrict__ rowptr,
                              unsigned* __restrict__ ebuf) {
    __shared__ int cnt[128];
    __shared__ int sc[128];
    int b = blockIdx.x;
    int tid = threadIdx.x;
    int base = binoff[b], end = binoff[b + 1];

    if (tid < 128) cnt[tid] = 0;
    __syncthreads();

    for (int i = base + tid; i < end; i += 256)
        atomicAdd(&cnt[binned[i] >> 20], 1);
    __syncthreads();

    if (tid < 128) sc[tid] = cnt[tid];
    __syncthreads();
    for (int off = 1; off < 128; off <<= 1) {
        int val = 0;
        if (tid < 128) {
            val = sc[tid];
            if (tid >= off) val += sc[tid - off];
        }
        __syncthreads();
        if (tid < 128) sc[tid] = val;
        __syncthreads();
    }
    if (tid < 128) {
        int excl = sc[tid] - cnt[tid];
        int v = b * 128 + tid;
        if (v < N_NODES) rowptr[v] = base + excl;
        cnt[tid] = excl;   // becomes running cursor
    }
    if (b == 0 && tid == 255) rowptr[N_NODES] = N_EDGES;
    __syncthreads();

    for (int i = base + tid; i < end; i += 256) {
        unsigned rec = binned[i];
        int dl = rec >> 20;
        int pos = base + atomicAdd(&cnt[dl], 1);
        ebuf[pos] = (rec & 0x1FFFFu) | (((rec >> 17) & 0x7u) << 20);
    }
}

// ---------------- per-layer kernels ----------------

// Gather: quarter-wave per node. At the random-line service-rate wall (R6/R10/R18).
__launch_bounds__(256, 6)
__global__ void gather_kernel(const int* __restrict__ rowptr,
                              const unsigned* __restrict__ ebuf,
                              const float* __restrict__ bond,    // [5,64]
                              const __half* __restrict__ hh,     // fp16 mirror
                              const float* __restrict__ hmast,   // fp32 master
                              __half* __restrict__ t16) {
    __shared__ float bond_s[5 * EMBED];
    for (int i = threadIdx.x; i < 5 * EMBED; i += 256) bond_s[i] = bond[i];
    __syncthreads();

    int sl = threadIdx.x & 15;    // uint2 slot: dims 4sl..4sl+3
    int d0 = sl * 4;
    int gq = (blockIdx.x * 256 + threadIdx.x) >> 4;   // global quarter id
    int nq = (gridDim.x * 256) >> 4;
    const uint2* hhq = (const uint2*)hh;    // 16 uint2 per node row

    for (int v = gq; v < N_NODES; v += nq) {
        int rb = rowptr[v], re = rowptr[v + 1];
        float4 a0 = {0,0,0,0}, a1 = {0,0,0,0}, a2 = {0,0,0,0}, a3 = {0,0,0,0};
        int e = rb;
        for (; e + 4 <= re; e += 4) {
            unsigned p0 = ebuf[e + 0];
            unsigned p1 = ebuf[e + 1];
            unsigned p2 = ebuf[e + 2];
            unsigned p3 = ebuf[e + 3];
            uint2 g0 = hhq[(size_t)(p0 & 0xFFFFFu) * 16 + sl];
            uint2 g1 = hhq[(size_t)(p1 & 0xFFFFFu) * 16 + sl];
            uint2 g2 = hhq[(size_t)(p2 & 0xFFFFFu) * 16 + sl];
            uint2 g3 = hhq[(size_t)(p3 & 0xFFFFFu) * 16 + sl];
            const float* c0 = &bond_s[(p0 >> 20) * EMBED + d0];
            const float* c1 = &bond_s[(p1 >> 20) * EMBED + d0];
            const float* c2 = &bond_s[(p2 >> 20) * EMBED + d0];
            const float* c3 = &bond_s[(p3 >> 20) * EMBED + d0];
            float2 f0a = __half22float2(*(const __half2*)&g0.x);
            float2 f0b = __half22float2(*(const __half2*)&g0.y);
            float2 f1a = __half22float2(*(const __half2*)&g1.x);
            float2 f1b = __half22float2(*(const __half2*)&g1.y);
            float2 f2a = __half22float2(*(const __half2*)&g2.x);
            float2 f2b = __half22float2(*(const __half2*)&g2.y);
            float2 f3a = __half22float2(*(const __half2*)&g3.x);
            float2 f3b = __half22float2(*(const __half2*)&g3.y);
            a0.x += fmaxf(f0a.x + c0[0], 0.f); a0.y += fmaxf(f0a.y + c0[1], 0.f);
            a0.z += fmaxf(f0b.x + c0[2], 0.f); a0.w += fmaxf(f0b.y + c0[3], 0.f);
            a1.x += fmaxf(f1a.x + c1[0], 0.f); a1.y += fmaxf(f1a.y + c1[1], 0.f);
            a1.z += fmaxf(f1b.x + c1[2], 0.f); a1.w += fmaxf(f1b.y + c1[3], 0.f);
            a2.x += fmaxf(f2a.x + c2[0], 0.f); a2.y += fmaxf(f2a.y + c2[1], 0.f);
            a2.z += fmaxf(f2b.x + c2[2], 0.f); a2.w += fmaxf(f2b.y + c2[3], 0.f);
            a3.x += fmaxf(f3a.x + c3[0], 0.f); a3.y += fmaxf(f3a.y + c3[1], 0.f);
            a3.z += fmaxf(f3b.x + c3[2], 0.f); a3.w += fmaxf(f3b.y + c3[3], 0.f);
        }
        for (; e < re; ++e) {
            unsigned p = ebuf[e];
            uint2 g = hhq[(size_t)(p & 0xFFFFFu) * 16 + sl];
            const float* c = &bond_s[(p >> 20) * EMBED + d0];
            float2 fa = __half22float2(*(const __half2*)&g.x);
            float2 fb = __half22float2(*(const __half2*)&g.y);
            a0.x += fmaxf(fa.x + c[0], 0.f); a0.y += fmaxf(fa.y + c[1], 0.f);
            a0.z += fmaxf(fb.x + c[2], 0.f); a0.w += fmaxf(fb.y + c[3], 0.f);
        }
        float inv = 1.0f / fmaxf((float)(re - rb), 1.0f);
        float4 hr = ((const float4*)hmast)[(size_t)v * 16 + sl];
        float tx = (a0.x + a1.x + a2.x + a3.x) * inv + hr.x;
        float ty = (a0.y + a1.y + a2.y + a3.y) * inv + hr.y;
        float tz = (a0.z + a1.z + a2.z + a3.z) * inv + hr.z;
        float tw = (a0.w + a1.w + a2.w + a3.w) * inv + hr.w;
        __half2 m0 = __floats2half2_rn(tx, ty);
        __half2 m1 = __floats2half2_rn(tz, tw);
        uint2 packed;
        packed.x = *(unsigned*)&m0;
        packed.y = *(unsigned*)&m1;
        ((uint2*)t16)[(size_t)v * 16 + sl] = packed;
    }
}

// Fused GEMM + BN stats + grid barrier + BN/relu/residual (layers 0,1).
// MFMA accumulators stay in registers across the barrier: h_pre16 round-trip removed.
// C/D layout: col=lane&15, row=(lane>>4)*4+reg [m89].
__launch_bounds__(256, 2)
__global__ void gemm_bn_fused(const _Float16* __restrict__ t16,
                              const _Float16* __restrict__ wfrag,  // packed
                              const float* __restrict__ bias,
                              const float* __restrict__ gamma,
                              const float* __restrict__ beta,
                              float* __restrict__ colsum,
                              float* __restrict__ colsq,
                              int* __restrict__ bar,
                              float* __restrict__ h,      // fp32 master (in: residual, out: new h)
                              __half* __restrict__ hh) {  // fp16 mirror out
    __shared__ float red[4][8][16];
    __shared__ float sscale[EMBED];
    __shared__ float sshift[EMBED];

    int lane = threadIdx.x & 63;
    int wblk = threadIdx.x >> 6;
    int quad = lane >> 4;
    int col  = lane & 15;
    int wid  = blockIdx.x * 4 + wblk;

    half8 bf[4][2];
#pragma unroll
    for (int nt = 0; nt < 4; ++nt)
#pragma unroll
        for (int kh = 0; kh < 2; ++kh)
            bf[nt][kh] = *(const half8*)(wfrag + ((size_t)(nt * 2 + kh) * 64 + lane) * 8);

    float bj[4];
#pragma unroll
    for (int nt = 0; nt < 4; ++nt) bj[nt] = bias[nt * 16 + col];

    float lsum[4] = {0.f, 0.f, 0.f, 0.f};
    float lsq [4] = {0.f, 0.f, 0.f, 0.f};
    floatx4 c[TPW][4];

#pragma unroll
    for (int k = 0; k < TPW; ++k) {
        int tile = wid + k * GB_WAVES;
        if (tile >= NTILES) continue;
        int base = tile * 16;
        const _Float16* arow = t16 + (size_t)(base + col) * 64 + quad * 8;
        half8 a0 = *(const half8*)(arow);
        half8 a1 = *(const half8*)(arow + 32);
#pragma unroll
        for (int nt = 0; nt < 4; ++nt) {
            floatx4 cc = {bj[nt], bj[nt], bj[nt], bj[nt]};
            cc = __builtin_amdgcn_mfma_f32_16x16x32_f16(a0, bf[nt][0], cc, 0, 0, 0);
            cc = __builtin_amdgcn_mfma_f32_16x16x32_f16(a1, bf[nt][1], cc, 0, 0, 0);
            c[k][nt] = cc;
#pragma unroll
            for (int r = 0; r < 4; ++r) {
                float v = cc[r];
                lsum[nt] += v;
                lsq[nt]  += v * v;
            }
        }
    }

#pragma unroll
    for (int nt = 0; nt < 4; ++nt) {
        lsum[nt] += __shfl_xor(lsum[nt], 16); lsum[nt] += __shfl_xor(lsum[nt], 32);
        lsq[nt]  += __shfl_xor(lsq[nt], 16);  lsq[nt]  += __shfl_xor(lsq[nt], 32);
    }
    if (lane < 16) {
#pragma unroll
        for (int nt = 0; nt < 4; ++nt) {
            red[wblk][nt * 2 + 0][lane] = lsum[nt];
            red[wblk][nt * 2 + 1][lane] = lsq[nt];
        }
    }
    __syncthreads();
    if (threadIdx.x < 128) {
        int f = threadIdx.x >> 4, l = threadIdx.x & 15;
        float s = red[0][f][l] + red[1][f][l] + red[2][f][l] + red[3][f][l];
        int nt = f >> 1;
        if ((f & 1) == 0) atomicAdd(&colsum[nt * 16 + l], s);
        else              atomicAdd(&colsq[nt * 16 + l], s);
    }

    grid_barrier(bar, GB_BLOCKS);

    // stats -> scale/shift once per block (agent-scope loads past per-XCD L2)
    if (threadIdx.x < EMBED) {
        int j = threadIdx.x;
        const float invN = 1.0f / (float)N_NODES;
        float s = __hip_atomic_load(&colsum[j], __ATOMIC_RELAXED, __HIP_MEMORY_SCOPE_AGENT);
        float q = __hip_atomic_load(&colsq[j],  __ATOMIC_RELAXED, __HIP_MEMORY_SCOPE_AGENT);
        float mu  = s * invN;
        float var = q * invN - mu * mu;
        float scv = rsqrtf(var + BN_EPS) * gamma[j];
        sscale[j] = scv;
        sshift[j] = beta[j] - mu * scv;
    }
    __syncthreads();

    float scr[4], shr[4];
#pragma unroll
    for (int nt = 0; nt < 4; ++nt) {
        scr[nt] = sscale[nt * 16 + col];
        shr[nt] = sshift[nt * 16 + col];
    }

#pragma unroll
    for (int k = 0; k < TPW; ++k) {
        int tile = wid + k * GB_WAVES;
        if (tile >= NTILES) continue;
        int base = tile * 16;
#pragma unroll
        for (int nt = 0; nt < 4; ++nt) {
#pragma unroll
            for (int r = 0; r < 4; ++r) {
                int node = base + quad * 4 + r;
                size_t off = (size_t)node * EMBED + nt * 16 + col;
                float y = fmaxf(c[k][nt][r] * scr[nt] + shr[nt], 0.0f);  // layers 0,1 relu
                float o = y + h[off];                                    // residual
                h[off] = o;
                hh[off] = __float2half(o);
            }
        }
    }
}

// Fused layer-2 GEMM + BN stats + barrier + BN/residual/graph-pool + barrier + pred.
// Final h never materialized. Pool exploits sorted graph_ids: tile-uniform graphs take
// one wave-reduced atomic per (nt,col); boundary tiles fall back to per-row atomics.
__launch_bounds__(256, 2)
__global__ void gemm_pool_fused(const _Float16* __restrict__ t16,
                                const _Float16* __restrict__ wfrag,
                                const float* __restrict__ bias,
                                const float* __restrict__ gamma,
                                const float* __restrict__ beta,
                                float* __restrict__ colsum,
                                float* __restrict__ colsq,
                                int* __restrict__ bar,       // two counters: bar[0], bar[1]
                                const float* __restrict__ h, // residual (layer-1 output)
                                const int* __restrict__ gid,
                                const int* __restrict__ gstart,
                                float* __restrict__ gsum,    // [N_GRAPHS, EMBED] zeroed
                                const float* __restrict__ predW, // [64,128]
                                const float* __restrict__ predb, // [128]
                                float* __restrict__ out) {       // [G, OUT_DIM]
    __shared__ float red[4][8][16];
    __shared__ float sscale[EMBED];
    __shared__ float sshift[EMBED];
    __shared__ float gm[EMBED];

    int lane = threadIdx.x & 63;
    int wblk = threadIdx.x >> 6;
    int quad = lane >> 4;
    int col  = lane & 15;
    int wid  = blockIdx.x * 4 + wblk;

    half8 bf[4][2];
#pragma unroll
    for (int nt = 0; nt < 4; ++nt)
#pragma unroll
        for (int kh = 0; kh < 2; ++kh)
            bf[nt][kh] = *(const half8*)(wfrag + ((size_t)(nt * 2 + kh) * 64 + lane) * 8);

    float bj[4];
#pragma unroll
    for (int nt = 0; nt < 4; ++nt) bj[nt] = bias[nt * 16 + col];

    float lsum[4] = {0.f, 0.f, 0.f, 0.f};
    float lsq [4] = {0.f, 0.f, 0.f, 0.f};
    floatx4 c[TPW][4];

#pragma unroll
    for (int k = 0; k < TPW; ++k) {
        int tile = wid + k * GB_WAVES;
        if (tile >= NTILES) continue;
        int base = tile * 16;
        const _Float16* arow = t16 + (size_t)(base + col) * 64 + quad * 8;
        half8 a0 = *(const half8*)(arow);
        half8 a1 = *(const half8*)(arow + 32);
#pragma unroll
        for (int nt = 0; nt < 4; ++nt) {
            floatx4 cc = {bj[nt], bj[nt], bj[nt], bj[nt]};
            cc = __builtin_amdgcn_mfma_f32_16x16x32_f16(a0, bf[nt][0], cc, 0, 0, 0);
            cc = __builtin_amdgcn_mfma_f32_16x16x32_f16(a1, bf[nt][1], cc, 0, 0, 0);
            c[k][nt] = cc;
#pragma unroll
            for (int r = 0; r < 4; ++r) {
                float v = cc[r];
                lsum[nt] += v;
                lsq[nt]  += v * v;
            }
        }
    }

#pragma unroll
    for (int nt = 0; nt < 4; ++nt) {
        lsum[nt] += __shfl_xor(lsum[nt], 16); lsum[nt] += __shfl_xor(lsum[nt], 32);
        lsq[nt]  += __shfl_xor(lsq[nt], 16);  lsq[nt]  += __shfl_xor(lsq[nt], 32);
    }
    if (lane < 16) {
#pragma unroll
        for (int nt = 0; nt < 4; ++nt) {
            red[wblk][nt * 2 + 0][lane] = lsum[nt];
            red[wblk][nt * 2 + 1][lane] = lsq[nt];
        }
    }
    __syncthreads();
    if (threadIdx.x < 128) {
        int f = threadIdx.x >> 4, l = threadIdx.x & 15;
        float s = red[0][f][l] + red[1][f][l] + red[2][f][l] + red[3][f][l];
        int nt = f >> 1;
        if ((f & 1) == 0) atomicAdd(&colsum[nt * 16 + l], s);
        else              atomicAdd(&colsq[nt * 16 + l], s);
    }

    grid_barrier(&bar[0], GB_BLOCKS);

    if (threadIdx.x < EMBED) {
        int j = threadIdx.x;
        const float invN = 1.0f / (float)N_NODES;
        float s = __hip_atomic_load(&colsum[j], __ATOMIC_RELAXED, __HIP_MEMORY_SCOPE_AGENT);
        float q = __hip_atomic_load(&colsq[j],  __ATOMIC_RELAXED, __HIP_MEMORY_SCOPE_AGENT);
        float mu  = s * invN;
        float var = q * invN - mu * mu;
        float scv = rsqrtf(var + BN_EPS) * gamma[j];   // no relu on last layer
        sscale[j] = scv;
        sshift[j] = beta[j] - mu * scv;
    }
    __syncthreads();

    float scr[4], shr[4];
#pragma unroll
    for (int nt = 0; nt < 4; ++nt) {
        scr[nt] = sscale[nt * 16 + col];
        shr[nt] = sshift[nt * 16 + col];
    }

#pragma unroll
    for (int k = 0; k < TPW; ++k) {
        int tile = wid + k * GB_WAVES;
        if (tile >= NTILES) continue;
        int base = tile * 16;
        int g0  = gid[base];
        int g15 = gid[base + 15];
        float val[4][4];   // [nt][r]
#pragma unroll
        for (int r = 0; r < 4; ++r) {
            int node = base + quad * 4 + r;
#pragma unroll
            for (int nt = 0; nt < 4; ++nt) {
                size_t off = (size_t)node * EMBED + nt * 16 + col;
                val[nt][r] = c[k][nt][r] * scr[nt] + shr[nt] + h[off];
            }
        }
        if (g0 == g15) {   // gid sorted -> whole tile is one graph (wave-uniform branch)
#pragma unroll
            for (int nt = 0; nt < 4; ++nt) {
                float s = val[nt][0] + val[nt][1] + val[nt][2] + val[nt][3];
                s += __shfl_xor(s, 16);
                s += __shfl_xor(s, 32);
                if (quad == 0)
                    atomicAdd(&gsum[(size_t)g0 * EMBED + nt * 16 + col], s);
            }
        } else {
#pragma unroll
            for (int r = 0; r < 4; ++r) {
                int node = base + quad * 4 + r;
                int g = gid[node];
#pragma unroll
                for (int nt = 0; nt < 4; ++nt)
                    atomicAdd(&gsum[(size_t)g * EMBED + nt * 16 + col], val[nt][r]);
            }
        }
    }

    grid_barrier(&bar[1], GB_BLOCKS);

    // pred: block per graph (grid-strided), gm row via LDS, 128 outputs
    for (int g = blockIdx.x; g < N_GRAPHS; g += gridDim.x) {
        int nb = gstart[g], ne = gstart[g + 1];
        float invc = 1.0f / fmaxf((float)(ne - nb), 1.0f);
        if (threadIdx.x < EMBED)
            gm[threadIdx.x] = __hip_atomic_load(&gsum[(size_t)g * EMBED + threadIdx.x],
                                                __ATOMIC_RELAXED, __HIP_MEMORY_SCOPE_AGENT) * invc;
        __syncthreads();
        if (threadIdx.x < OUT_DIM) {
            float acc = predb[threadIdx.x];
#pragma unroll
            for (int d = 0; d < EMBED; ++d)
                acc += gm[d] * predW[d * OUT_DIM + threadIdx.x];
            out[g * OUT_DIM + threadIdx.x] = acc;
        }
        __syncthreads();
    }
}

// ---------------- launch ----------------

extern "C" void kernel_launch(void* const* d_in, const int* in_sizes, int n_in,
                              void* d_out, int out_size, void* d_ws, size_t ws_size,
                              hipStream_t stream) {
    const int*   nfeat      = (const int*)d_in[0];
    const int*   efeat      = (const int*)d_in[1];
    const int*   src        = (const int*)d_in[2];
    const int*   dst        = (const int*)d_in[3];
    const int*   gid        = (const int*)d_in[4];
    const float* atom_embed = (const float*)d_in[5];
    const float* bond_embed = (const float*)d_in[6];  // [3,5,64]
    const float* conv_W     = (const float*)d_in[7];  // [3,64,64]
    const float* conv_b     = (const float*)d_in[8];  // [3,64]
    const float* bn_gamma   = (const float*)d_in[9];  // [3,64]
    const float* bn_beta    = (const float*)d_in[10]; // [3,64]
    const float* pred_W     = (const float*)d_in[11]; // [64,128]
    const float* pred_b     = (const float*)d_in[12]; // [128]
    float* out = (float*)d_out;

    char* wsb = (char*)d_ws;
    float*     h        = (float*)wsb;                  wsb += (size_t)N_NODES * EMBED * 4;
    _Float16*  t16      = (_Float16*)wsb;               wsb += (size_t)N_NODES * EMBED * 2;
    __half*    hh       = (__half*)wsb;                 wsb += (size_t)N_NODES * EMBED * 2;
    _Float16*  wfrag    = (_Float16*)wsb;               wsb += (size_t)3 * 4096 * 2;
    unsigned*  binned   = (unsigned*)wsb;               wsb += (size_t)N_EDGES * 4;
    unsigned*  ebuf     = (unsigned*)wsb;               wsb += (size_t)N_EDGES * 4;
    int*       blockhist= (int*)wsb;                    wsb += (size_t)NBINS * NSCB * 4;
    int*       gofs     = (int*)wsb;                    wsb += (size_t)NBINS * NSCB * 4;
    int*       total    = (int*)wsb;                    wsb += (size_t)NBINS * 4;
    int*       binoff   = (int*)wsb;                    wsb += (size_t)(NBINS + 1) * 4;
    int*       rowptr   = (int*)wsb;                    wsb += (size_t)(N_NODES + 1) * 4;
    int*       gstart   = (int*)wsb;                    wsb += (size_t)(N_GRAPHS + 1) * 4;
    float*     colsum   = (float*)wsb;                  wsb += (size_t)3 * EMBED * 4;  // must stay
    float*     colsq    = (float*)wsb;                  wsb += (size_t)3 * EMBED * 4;  // adjacent
    float*     gsum     = (float*)wsb;                  wsb += (size_t)N_GRAPHS * EMBED * 4;
    int*       bar      = (int*)wsb;                    wsb += (size_t)8 * 4;

    embed_kernel<<<(N_NODES * 16 + 255) / 256, 256, 0, stream>>>(
        nfeat, atom_embed, (float4*)h, hh, gid, gstart, gsum);
    hist2_kernel<<<NSCB, 256, 0, stream>>>(dst, blockhist);
    binreduce_kernel<<<NBINS, NSCB, 0, stream>>>(blockhist, gofs, total);
    binscan_kernel<<<1, 1024, 0, stream>>>(total, binoff, colsum, bar, conv_W, wfrag);
    binscatter_kernel<<<NSCB, 256, 0, stream>>>(src, dst, efeat, binoff, gofs, binned);
    bincsr_kernel<<<NBINS, 256, 0, stream>>>(binned, binoff, rowptr, ebuf);

    for (int i = 0; i < 3; ++i) {
        gather_kernel<<<1536, 256, 0, stream>>>(
            rowptr, ebuf, bond_embed + i * 5 * EMBED, hh, h, (__half*)t16);
        const _Float16* wf = wfrag + (size_t)i * 4096;
        const float* bi = conv_b + (size_t)i * EMBED;
        const float* ga = bn_gamma + (size_t)i * EMBED;
        const float* be = bn_beta + (size_t)i * EMBED;
        float* cs = colsum + (size_t)i * EMBED;
        float* cq = colsq + (size_t)i * EMBED;
        if (i != 2) {
            gemm_bn_fused<<<GB_BLOCKS, 256, 0, stream>>>(
                t16, wf, bi, ga, be, cs, cq, bar + i, h, hh);
        } else {
            gemm_pool_fused<<<GB_BLOCKS, 256, 0, stream>>>(
                t16, wf, bi, ga, be, cs, cq, bar + 2,
                h, gid, gstart, gsum, pred_W, pred_b, out);
        }
    }
}

// Round 3
// 379.478 us; speedup vs baseline: 1.3088x; 1.3088x over previous
//
#include <hip/hip_runtime.h>
#include <hip/hip_fp16.h>

#define N_NODES 100000
#define N_EDGES 1000000
#define N_GRAPHS 1000
#define EMBED 64
#define OUT_DIM 128
#define BN_EPS 1e-5f
#define NBINS 782                          // dst>>7 -> 128 nodes per bin
#define NSCB 512                           // scatter blocks (fixed edge ranges)
#define EPB ((N_EDGES + NSCB - 1) / NSCB)  // 1954 edges per block
#define NTILES (N_NODES / 16)              // 6250 exact

#define GB_BLOCKS 512                      // fused gemm grid: 2 blocks/CU guaranteed resident
#define GB_WAVES (GB_BLOCKS * 4)           // 2048 waves
#define TPW 4                              // ceil(6250/2048) tiles per wave

typedef _Float16 half8 __attribute__((ext_vector_type(8)));
typedef float floatx4 __attribute__((ext_vector_type(4)));

// Software grid barrier v2 (graph-capture-safe).
// R2 lesson: ACQUIRE polling emits a cache-invalidate per iteration (gfx94x+ agent-scope
// acquire) -> 512 spinners = invalidation storm that stretched 10us of work to 166us.
// v2: relaxed fetch_add on counter line; last arriver release-stores a FLAG on a
// DIFFERENT cacheline; waiters poll flag with RELAXED loads (no invalidates) and
// fence once on exit. s_sleep(16) ~0.4us poll quantum. Counter at p[0], flag at p[1024].
__device__ __forceinline__ void grid_barrier(int* p, int target) {
    __syncthreads();
    if (threadIdx.x == 0) {
        __threadfence();
        int old = __hip_atomic_fetch_add(p, 1, __ATOMIC_RELAXED, __HIP_MEMORY_SCOPE_AGENT);
        if (old == target - 1) {
            __hip_atomic_store(p + 1024, 1, __ATOMIC_RELEASE, __HIP_MEMORY_SCOPE_AGENT);
        } else {
            int spins = 0;
            while (__hip_atomic_load(p + 1024, __ATOMIC_RELAXED, __HIP_MEMORY_SCOPE_AGENT) == 0) {
                __builtin_amdgcn_s_sleep(16);
                if (++spins > (1 << 20)) break;   // ~0.5s failsafe: visible failure beats deadlock
            }
        }
        __threadfence();
    }
    __syncthreads();
}

// ---------------- one-time structure kernels ----------------

// writes fp32 h and fp16 mirror; builds graph boundaries; zeroes gsum
__global__ void embed_kernel(const int* __restrict__ nfeat,
                             const float* __restrict__ atom_embed,
                             float4* __restrict__ h4,
                             __half* __restrict__ hh,
                             const int* __restrict__ gid,
                             int* __restrict__ gstart,
                             float* __restrict__ gsum) {
    int idx = blockIdx.x * blockDim.x + threadIdx.x;   // one float4 each
    if (idx <= N_NODES) {   // folded gbound
        int cur  = (idx < N_NODES) ? gid[idx] : N_GRAPHS;
        int prev = (idx == 0) ? -1 : gid[idx - 1];
        for (int g = prev + 1; g <= cur; ++g) gstart[g] = idx;
    }
    if (idx < N_GRAPHS * EMBED) gsum[idx] = 0.0f;
    if (idx >= N_NODES * 16) return;
    int v = idx >> 4, q = idx & 15;
    const float4* ae = (const float4*)atom_embed;
    float4 val = ae[nfeat[v] * 16 + q];
    h4[idx] = val;
    __half2 m0 = __floats2half2_rn(val.x, val.y);
    __half2 m1 = __floats2half2_rn(val.z, val.w);
    uint2 packed;
    packed.x = *(unsigned*)&m0;
    packed.y = *(unsigned*)&m1;
    ((uint2*)hh)[idx] = packed;
}

// per-block LDS histogram of its fixed edge range -> blockhist[bin][block]
__global__ void hist2_kernel(const int* __restrict__ dst, int* __restrict__ blockhist) {
    __shared__ int hist[NBINS];
    for (int i = threadIdx.x; i < NBINS; i += 256) hist[i] = 0;
    __syncthreads();
    int b = blockIdx.x;
    int e0 = b * EPB, e1 = min(e0 + EPB, N_EDGES);
    for (int e = e0 + threadIdx.x; e < e1; e += 256)
        atomicAdd(&hist[dst[e] >> 7], 1);
    __syncthreads();
    for (int i = threadIdx.x; i < NBINS; i += 256)
        blockhist[i * NSCB + b] = hist[i];
}

// one block per bin: exclusive scan of its 512 block-counts -> gofs; total per bin
__global__ void binreduce_kernel(const int* __restrict__ blockhist,
                                 int* __restrict__ gofs, int* __restrict__ total) {
    __shared__ int sm[NSCB];
    int bin = blockIdx.x;
    int i = threadIdx.x;   // 0..511
    int orig = blockhist[bin * NSCB + i];
    sm[i] = orig;
    __syncthreads();
    for (int off = 1; off < NSCB; off <<= 1) {
        int val = sm[i];
        if (i >= off) val += sm[i - off];
        __syncthreads();
        sm[i] = val;
        __syncthreads();
    }
    gofs[bin * NSCB + i] = sm[i] - orig;   // exclusive within bin
    if (i == NSCB - 1) total[bin] = sm[i];
}

// scan 782 bin totals -> binoff (exclusive); zeroes BN stats + barrier block; packs W frags
__global__ void binscan_kernel(const int* __restrict__ total,
                               int* __restrict__ binoff, float* __restrict__ stats,
                               int* __restrict__ bar,
                               const float* __restrict__ conv_W,
                               _Float16* __restrict__ wfrag) {
    __shared__ int sm[1024];
    int i = threadIdx.x;
    if (i < 6 * EMBED) stats[i] = 0.0f;
    for (int s = i; s < 2048; s += 1024) bar[s] = 0;   // counters + flags
    // folded wpack: 3 layers x 512 slots
    for (int s = i; s < 3 * 512; s += 1024) {
        int L = s >> 9, slot = s & 511;
        int lane = slot & 63;
        int f = slot >> 6;          // nt*2+kh
        int nt = f >> 1, kh = f & 1;
        int n  = nt * 16 + (lane & 15);
        int k0 = kh * 32 + (lane >> 4) * 8;
        const float* W = conv_W + L * 4096;
        _Float16* out = wfrag + L * 4096;
#pragma unroll
        for (int j = 0; j < 8; ++j)
            out[slot * 8 + j] = (_Float16)W[(k0 + j) * 64 + n];
    }
    int orig = (i < NBINS) ? total[i] : 0;
    sm[i] = orig;
    __syncthreads();
    for (int off = 1; off < 1024; off <<= 1) {
        int val = sm[i];
        if (i >= off) val += sm[i - off];
        __syncthreads();
        sm[i] = val;
        __syncthreads();
    }
    if (i < NBINS) binoff[i] = sm[i] - orig;
    if (i == 0) binoff[NBINS] = N_EDGES;
}

// deterministic multisplit scatter: LDS cursors seeded from binoff+gofs.
__global__ void binscatter_kernel(const int* __restrict__ src, const int* __restrict__ dst,
                                  const int* __restrict__ efeat,
                                  const int* __restrict__ binoff, const int* __restrict__ gofs,
                                  unsigned* __restrict__ binned) {
    __shared__ int cur[NBINS];
    int b = blockIdx.x;
    for (int i = threadIdx.x; i < NBINS; i += 256)
        cur[i] = binoff[i] + gofs[i * NSCB + b];
    __syncthreads();
    int e0 = b * EPB, e1 = min(e0 + EPB, N_EDGES);
    for (int e = e0 + threadIdx.x; e < e1; e += 256) {
        int t = dst[e];
        int bin = t >> 7;
        int pos = atomicAdd(&cur[bin], 1);   // LDS atomic
        binned[pos] = (unsigned)src[e] | ((unsigned)efeat[e] << 17)
                    | ((unsigned)(t & 127) << 20);
    }
}

// one block per bin: local deg count + local scan -> rowptr slice + ebuf region
__global__ void bincsr_kernel(const unsigned* __restrict__ binned,
                              const int* __restrict__ binoff,
                              int* __restrict__ rowptr,
                              unsigned* __restrict__ ebuf) {
    __shared__ int cnt[128];
    __shared__ int sc[128];
    int b = blockIdx.x;
    int tid = threadIdx.x;
    int base = binoff[b], end = binoff[b + 1];

    if (tid < 128) cnt[tid] = 0;
    __syncthreads();

    for (int i = base + tid; i < end; i += 256)
        atomicAdd(&cnt[binned[i] >> 20], 1);
    __syncthreads();

    if (tid < 128) sc[tid] = cnt[tid];
    __syncthreads();
    for (int off = 1; off < 128; off <<= 1) {
        int val = 0;
        if (tid < 128) {
            val = sc[tid];
            if (tid >= off) val += sc[tid - off];
        }
        __syncthreads();
        if (tid < 128) sc[tid] = val;
        __syncthreads();
    }
    if (tid < 128) {
        int excl = sc[tid] - cnt[tid];
        int v = b * 128 + tid;
        if (v < N_NODES) rowptr[v] = base + excl;
        cnt[tid] = excl;   // becomes running cursor
    }
    if (b == 0 && tid == 255) rowptr[N_NODES] = N_EDGES;
    __syncthreads();

    for (int i = base + tid; i < end; i += 256) {
        unsigned rec = binned[i];
        int dl = rec >> 20;
        int pos = base + atomicAdd(&cnt[dl], 1);
        ebuf[pos] = (rec & 0x1FFFFu) | (((rec >> 17) & 0x7u) << 20);
    }
}

// ---------------- per-layer kernels ----------------

// Gather: quarter-wave per node. At the random-line service-rate wall (R6/R10/R18).
__launch_bounds__(256, 6)
__global__ void gather_kernel(const int* __restrict__ rowptr,
                              const unsigned* __restrict__ ebuf,
                              const float* __restrict__ bond,    // [5,64]
                              const __half* __restrict__ hh,     // fp16 mirror
                              const float* __restrict__ hmast,   // fp32 master
                              __half* __restrict__ t16) {
    __shared__ float bond_s[5 * EMBED];
    for (int i = threadIdx.x; i < 5 * EMBED; i += 256) bond_s[i] = bond[i];
    __syncthreads();

    int sl = threadIdx.x & 15;    // uint2 slot: dims 4sl..4sl+3
    int d0 = sl * 4;
    int gq = (blockIdx.x * 256 + threadIdx.x) >> 4;   // global quarter id
    int nq = (gridDim.x * 256) >> 4;
    const uint2* hhq = (const uint2*)hh;    // 16 uint2 per node row

    for (int v = gq; v < N_NODES; v += nq) {
        int rb = rowptr[v], re = rowptr[v + 1];
        float4 a0 = {0,0,0,0}, a1 = {0,0,0,0}, a2 = {0,0,0,0}, a3 = {0,0,0,0};
        int e = rb;
        for (; e + 4 <= re; e += 4) {
            unsigned p0 = ebuf[e + 0];
            unsigned p1 = ebuf[e + 1];
            unsigned p2 = ebuf[e + 2];
            unsigned p3 = ebuf[e + 3];
            uint2 g0 = hhq[(size_t)(p0 & 0xFFFFFu) * 16 + sl];
            uint2 g1 = hhq[(size_t)(p1 & 0xFFFFFu) * 16 + sl];
            uint2 g2 = hhq[(size_t)(p2 & 0xFFFFFu) * 16 + sl];
            uint2 g3 = hhq[(size_t)(p3 & 0xFFFFFu) * 16 + sl];
            const float* c0 = &bond_s[(p0 >> 20) * EMBED + d0];
            const float* c1 = &bond_s[(p1 >> 20) * EMBED + d0];
            const float* c2 = &bond_s[(p2 >> 20) * EMBED + d0];
            const float* c3 = &bond_s[(p3 >> 20) * EMBED + d0];
            float2 f0a = __half22float2(*(const __half2*)&g0.x);
            float2 f0b = __half22float2(*(const __half2*)&g0.y);
            float2 f1a = __half22float2(*(const __half2*)&g1.x);
            float2 f1b = __half22float2(*(const __half2*)&g1.y);
            float2 f2a = __half22float2(*(const __half2*)&g2.x);
            float2 f2b = __half22float2(*(const __half2*)&g2.y);
            float2 f3a = __half22float2(*(const __half2*)&g3.x);
            float2 f3b = __half22float2(*(const __half2*)&g3.y);
            a0.x += fmaxf(f0a.x + c0[0], 0.f); a0.y += fmaxf(f0a.y + c0[1], 0.f);
            a0.z += fmaxf(f0b.x + c0[2], 0.f); a0.w += fmaxf(f0b.y + c0[3], 0.f);
            a1.x += fmaxf(f1a.x + c1[0], 0.f); a1.y += fmaxf(f1a.y + c1[1], 0.f);
            a1.z += fmaxf(f1b.x + c1[2], 0.f); a1.w += fmaxf(f1b.y + c1[3], 0.f);
            a2.x += fmaxf(f2a.x + c2[0], 0.f); a2.y += fmaxf(f2a.y + c2[1], 0.f);
            a2.z += fmaxf(f2b.x + c2[2], 0.f); a2.w += fmaxf(f2b.y + c2[3], 0.f);
            a3.x += fmaxf(f3a.x + c3[0], 0.f); a3.y += fmaxf(f3a.y + c3[1], 0.f);
            a3.z += fmaxf(f3b.x + c3[2], 0.f); a3.w += fmaxf(f3b.y + c3[3], 0.f);
        }
        for (; e < re; ++e) {
            unsigned p = ebuf[e];
            uint2 g = hhq[(size_t)(p & 0xFFFFFu) * 16 + sl];
            const float* c = &bond_s[(p >> 20) * EMBED + d0];
            float2 fa = __half22float2(*(const __half2*)&g.x);
            float2 fb = __half22float2(*(const __half2*)&g.y);
            a0.x += fmaxf(fa.x + c[0], 0.f); a0.y += fmaxf(fa.y + c[1], 0.f);
            a0.z += fmaxf(fb.x + c[2], 0.f); a0.w += fmaxf(fb.y + c[3], 0.f);
        }
        float inv = 1.0f / fmaxf((float)(re - rb), 1.0f);
        float4 hr = ((const float4*)hmast)[(size_t)v * 16 + sl];
        float tx = (a0.x + a1.x + a2.x + a3.x) * inv + hr.x;
        float ty = (a0.y + a1.y + a2.y + a3.y) * inv + hr.y;
        float tz = (a0.z + a1.z + a2.z + a3.z) * inv + hr.z;
        float tw = (a0.w + a1.w + a2.w + a3.w) * inv + hr.w;
        __half2 m0 = __floats2half2_rn(tx, ty);
        __half2 m1 = __floats2half2_rn(tz, tw);
        uint2 packed;
        packed.x = *(unsigned*)&m0;
        packed.y = *(unsigned*)&m1;
        ((uint2*)t16)[(size_t)v * 16 + sl] = packed;
    }
}

// Fused GEMM + BN stats + grid barrier + BN/relu/residual (layers 0,1).
// MFMA accumulators stay in registers across the barrier: h_pre16 round-trip removed.
// C/D layout: col=lane&15, row=(lane>>4)*4+reg [m89].
__launch_bounds__(256, 2)
__global__ void gemm_bn_fused(const _Float16* __restrict__ t16,
                              const _Float16* __restrict__ wfrag,  // packed
                              const float* __restrict__ bias,
                              const float* __restrict__ gamma,
                              const float* __restrict__ beta,
                              float* __restrict__ colsum,
                              float* __restrict__ colsq,
                              int* __restrict__ bar,
                              float* __restrict__ h,      // fp32 master (in: residual, out: new h)
                              __half* __restrict__ hh) {  // fp16 mirror out
    __shared__ float red[4][8][16];
    __shared__ float sscale[EMBED];
    __shared__ float sshift[EMBED];

    int lane = threadIdx.x & 63;
    int wblk = threadIdx.x >> 6;
    int quad = lane >> 4;
    int col  = lane & 15;
    int wid  = blockIdx.x * 4 + wblk;

    half8 bf[4][2];
#pragma unroll
    for (int nt = 0; nt < 4; ++nt)
#pragma unroll
        for (int kh = 0; kh < 2; ++kh)
            bf[nt][kh] = *(const half8*)(wfrag + ((size_t)(nt * 2 + kh) * 64 + lane) * 8);

    float bj[4];
#pragma unroll
    for (int nt = 0; nt < 4; ++nt) bj[nt] = bias[nt * 16 + col];

    float lsum[4] = {0.f, 0.f, 0.f, 0.f};
    float lsq [4] = {0.f, 0.f, 0.f, 0.f};
    floatx4 c[TPW][4];

#pragma unroll
    for (int k = 0; k < TPW; ++k) {
        int tile = wid + k * GB_WAVES;
        if (tile >= NTILES) continue;
        int base = tile * 16;
        const _Float16* arow = t16 + (size_t)(base + col) * 64 + quad * 8;
        half8 a0 = *(const half8*)(arow);
        half8 a1 = *(const half8*)(arow + 32);
#pragma unroll
        for (int nt = 0; nt < 4; ++nt) {
            floatx4 cc = {bj[nt], bj[nt], bj[nt], bj[nt]};
            cc = __builtin_amdgcn_mfma_f32_16x16x32_f16(a0, bf[nt][0], cc, 0, 0, 0);
            cc = __builtin_amdgcn_mfma_f32_16x16x32_f16(a1, bf[nt][1], cc, 0, 0, 0);
            c[k][nt] = cc;
#pragma unroll
            for (int r = 0; r < 4; ++r) {
                float v = cc[r];
                lsum[nt] += v;
                lsq[nt]  += v * v;
            }
        }
    }

#pragma unroll
    for (int nt = 0; nt < 4; ++nt) {
        lsum[nt] += __shfl_xor(lsum[nt], 16); lsum[nt] += __shfl_xor(lsum[nt], 32);
        lsq[nt]  += __shfl_xor(lsq[nt], 16);  lsq[nt]  += __shfl_xor(lsq[nt], 32);
    }
    if (lane < 16) {
#pragma unroll
        for (int nt = 0; nt < 4; ++nt) {
            red[wblk][nt * 2 + 0][lane] = lsum[nt];
            red[wblk][nt * 2 + 1][lane] = lsq[nt];
        }
    }
    __syncthreads();
    if (threadIdx.x < 128) {
        int f = threadIdx.x >> 4, l = threadIdx.x & 15;
        float s = red[0][f][l] + red[1][f][l] + red[2][f][l] + red[3][f][l];
        int nt = f >> 1;
        if ((f & 1) == 0) atomicAdd(&colsum[nt * 16 + l], s);
        else              atomicAdd(&colsq[nt * 16 + l], s);
    }

    grid_barrier(bar, GB_BLOCKS);

    // stats -> scale/shift once per block
    if (threadIdx.x < EMBED) {
        int j = threadIdx.x;
        const float invN = 1.0f / (float)N_NODES;
        float s = __hip_atomic_load(&colsum[j], __ATOMIC_RELAXED, __HIP_MEMORY_SCOPE_AGENT);
        float q = __hip_atomic_load(&colsq[j],  __ATOMIC_RELAXED, __HIP_MEMORY_SCOPE_AGENT);
        float mu  = s * invN;
        float var = q * invN - mu * mu;
        float scv = rsqrtf(var + BN_EPS) * gamma[j];
        sscale[j] = scv;
        sshift[j] = beta[j] - mu * scv;
    }
    __syncthreads();

    float scr[4], shr[4];
#pragma unroll
    for (int nt = 0; nt < 4; ++nt) {
        scr[nt] = sscale[nt * 16 + col];
        shr[nt] = sshift[nt * 16 + col];
    }

#pragma unroll
    for (int k = 0; k < TPW; ++k) {
        int tile = wid + k * GB_WAVES;
        if (tile >= NTILES) continue;
        int base = tile * 16;
#pragma unroll
        for (int nt = 0; nt < 4; ++nt) {
#pragma unroll
            for (int r = 0; r < 4; ++r) {
                int node = base + quad * 4 + r;
                size_t off = (size_t)node * EMBED + nt * 16 + col;
                float y = fmaxf(c[k][nt][r] * scr[nt] + shr[nt], 0.0f);  // layers 0,1 relu
                float o = y + h[off];                                    // residual
                h[off] = o;
                hh[off] = __float2half(o);
            }
        }
    }
}

// Fused layer-2 GEMM + BN stats + barrier + BN/residual/graph-pool + barrier + pred.
// Final h never materialized. Pool exploits sorted graph_ids: tile-uniform graphs take
// one wave-reduced atomic per (nt,col); boundary tiles fall back to per-row atomics.
__launch_bounds__(256, 2)
__global__ void gemm_pool_fused(const _Float16* __restrict__ t16,
                                const _Float16* __restrict__ wfrag,
                                const float* __restrict__ bias,
                                const float* __restrict__ gamma,
                                const float* __restrict__ beta,
                                float* __restrict__ colsum,
                                float* __restrict__ colsq,
                                int* __restrict__ bar,       // counters p, p+32; flags p+1024,...
                                const float* __restrict__ h, // residual (layer-1 output)
                                const int* __restrict__ gid,
                                const int* __restrict__ gstart,
                                float* __restrict__ gsum,    // [N_GRAPHS, EMBED] zeroed
                                const float* __restrict__ predW, // [64,128]
                                const float* __restrict__ predb, // [128]
                                float* __restrict__ out) {       // [G, OUT_DIM]
    __shared__ float red[4][8][16];
    __shared__ float sscale[EMBED];
    __shared__ float sshift[EMBED];
    __shared__ float gm[EMBED];

    int lane = threadIdx.x & 63;
    int wblk = threadIdx.x >> 6;
    int quad = lane >> 4;
    int col  = lane & 15;
    int wid  = blockIdx.x * 4 + wblk;

    half8 bf[4][2];
#pragma unroll
    for (int nt = 0; nt < 4; ++nt)
#pragma unroll
        for (int kh = 0; kh < 2; ++kh)
            bf[nt][kh] = *(const half8*)(wfrag + ((size_t)(nt * 2 + kh) * 64 + lane) * 8);

    float bj[4];
#pragma unroll
    for (int nt = 0; nt < 4; ++nt) bj[nt] = bias[nt * 16 + col];

    float lsum[4] = {0.f, 0.f, 0.f, 0.f};
    float lsq [4] = {0.f, 0.f, 0.f, 0.f};
    floatx4 c[TPW][4];

#pragma unroll
    for (int k = 0; k < TPW; ++k) {
        int tile = wid + k * GB_WAVES;
        if (tile >= NTILES) continue;
        int base = tile * 16;
        const _Float16* arow = t16 + (size_t)(base + col) * 64 + quad * 8;
        half8 a0 = *(const half8*)(arow);
        half8 a1 = *(const half8*)(arow + 32);
#pragma unroll
        for (int nt = 0; nt < 4; ++nt) {
            floatx4 cc = {bj[nt], bj[nt], bj[nt], bj[nt]};
            cc = __builtin_amdgcn_mfma_f32_16x16x32_f16(a0, bf[nt][0], cc, 0, 0, 0);
            cc = __builtin_amdgcn_mfma_f32_16x16x32_f16(a1, bf[nt][1], cc, 0, 0, 0);
            c[k][nt] = cc;
#pragma unroll
            for (int r = 0; r < 4; ++r) {
                float v = cc[r];
                lsum[nt] += v;
                lsq[nt]  += v * v;
            }
        }
    }

#pragma unroll
    for (int nt = 0; nt < 4; ++nt) {
        lsum[nt] += __shfl_xor(lsum[nt], 16); lsum[nt] += __shfl_xor(lsum[nt], 32);
        lsq[nt]  += __shfl_xor(lsq[nt], 16);  lsq[nt]  += __shfl_xor(lsq[nt], 32);
    }
    if (lane < 16) {
#pragma unroll
        for (int nt = 0; nt < 4; ++nt) {
            red[wblk][nt * 2 + 0][lane] = lsum[nt];
            red[wblk][nt * 2 + 1][lane] = lsq[nt];
        }
    }
    __syncthreads();
    if (threadIdx.x < 128) {
        int f = threadIdx.x >> 4, l = threadIdx.x & 15;
        float s = red[0][f][l] + red[1][f][l] + red[2][f][l] + red[3][f][l];
        int nt = f >> 1;
        if ((f & 1) == 0) atomicAdd(&colsum[nt * 16 + l], s);
        else              atomicAdd(&colsq[nt * 16 + l], s);
    }

    grid_barrier(bar, GB_BLOCKS);

    if (threadIdx.x < EMBED) {
        int j = threadIdx.x;
        const float invN = 1.0f / (float)N_NODES;
        float s = __hip_atomic_load(&colsum[j], __ATOMIC_RELAXED, __HIP_MEMORY_SCOPE_AGENT);
        float q = __hip_atomic_load(&colsq[j],  __ATOMIC_RELAXED, __HIP_MEMORY_SCOPE_AGENT);
        float mu  = s * invN;
        float var = q * invN - mu * mu;
        float scv = rsqrtf(var + BN_EPS) * gamma[j];   // no relu on last layer
        sscale[j] = scv;
        sshift[j] = beta[j] - mu * scv;
    }
    __syncthreads();

    float scr[4], shr[4];
#pragma unroll
    for (int nt = 0; nt < 4; ++nt) {
        scr[nt] = sscale[nt * 16 + col];
        shr[nt] = sshift[nt * 16 + col];
    }

#pragma unroll
    for (int k = 0; k < TPW; ++k) {
        int tile = wid + k * GB_WAVES;
        if (tile >= NTILES) continue;
        int base = tile * 16;
        int g0  = gid[base];
        int g15 = gid[base + 15];
        float val[4][4];   // [nt][r]
#pragma unroll
        for (int r = 0; r < 4; ++r) {
            int node = base + quad * 4 + r;
#pragma unroll
            for (int nt = 0; nt < 4; ++nt) {
                size_t off = (size_t)node * EMBED + nt * 16 + col;
                val[nt][r] = c[k][nt][r] * scr[nt] + shr[nt] + h[off];
            }
        }
        if (g0 == g15) {   // gid sorted -> whole tile is one graph (wave-uniform branch)
#pragma unroll
            for (int nt = 0; nt < 4; ++nt) {
                float s = val[nt][0] + val[nt][1] + val[nt][2] + val[nt][3];
                s += __shfl_xor(s, 16);
                s += __shfl_xor(s, 32);
                if (quad == 0)
                    atomicAdd(&gsum[(size_t)g0 * EMBED + nt * 16 + col], s);
            }
        } else {
#pragma unroll
            for (int r = 0; r < 4; ++r) {
                int node = base + quad * 4 + r;
                int g = gid[node];
#pragma unroll
                for (int nt = 0; nt < 4; ++nt)
                    atomicAdd(&gsum[(size_t)g * EMBED + nt * 16 + col], val[nt][r]);
            }
        }
    }

    grid_barrier(bar + 32, GB_BLOCKS);

    // pred: block per graph (grid-strided), gm row via LDS, 128 outputs
    for (int g = blockIdx.x; g < N_GRAPHS; g += gridDim.x) {
        int nb = gstart[g], ne = gstart[g + 1];
        float invc = 1.0f / fmaxf((float)(ne - nb), 1.0f);
        if (threadIdx.x < EMBED)
            gm[threadIdx.x] = __hip_atomic_load(&gsum[(size_t)g * EMBED + threadIdx.x],
                                                __ATOMIC_RELAXED, __HIP_MEMORY_SCOPE_AGENT) * invc;
        __syncthreads();
        if (threadIdx.x < OUT_DIM) {
            float acc = predb[threadIdx.x];
#pragma unroll
            for (int d = 0; d < EMBED; ++d)
                acc += gm[d] * predW[d * OUT_DIM + threadIdx.x];
            out[g * OUT_DIM + threadIdx.x] = acc;
        }
        __syncthreads();
    }
}

// ---------------- launch ----------------

extern "C" void kernel_launch(void* const* d_in, const int* in_sizes, int n_in,
                              void* d_out, int out_size, void* d_ws, size_t ws_size,
                              hipStream_t stream) {
    const int*   nfeat      = (const int*)d_in[0];
    const int*   efeat      = (const int*)d_in[1];
    const int*   src        = (const int*)d_in[2];
    const int*   dst        = (const int*)d_in[3];
    const int*   gid        = (const int*)d_in[4];
    const float* atom_embed = (const float*)d_in[5];
    const float* bond_embed = (const float*)d_in[6];  // [3,5,64]
    const float* conv_W     = (const float*)d_in[7];  // [3,64,64]
    const float* conv_b     = (const float*)d_in[8];  // [3,64]
    const float* bn_gamma   = (const float*)d_in[9];  // [3,64]
    const float* bn_beta    = (const float*)d_in[10]; // [3,64]
    const float* pred_W     = (const float*)d_in[11]; // [64,128]
    const float* pred_b     = (const float*)d_in[12]; // [128]
    float* out = (float*)d_out;

    char* wsb = (char*)d_ws;
    float*     h        = (float*)wsb;                  wsb += (size_t)N_NODES * EMBED * 4;
    _Float16*  t16      = (_Float16*)wsb;               wsb += (size_t)N_NODES * EMBED * 2;
    __half*    hh       = (__half*)wsb;                 wsb += (size_t)N_NODES * EMBED * 2;
    _Float16*  wfrag    = (_Float16*)wsb;               wsb += (size_t)3 * 4096 * 2;
    unsigned*  binned   = (unsigned*)wsb;               wsb += (size_t)N_EDGES * 4;
    unsigned*  ebuf     = (unsigned*)wsb;               wsb += (size_t)N_EDGES * 4;
    int*       blockhist= (int*)wsb;                    wsb += (size_t)NBINS * NSCB * 4;
    int*       gofs     = (int*)wsb;                    wsb += (size_t)NBINS * NSCB * 4;
    int*       total    = (int*)wsb;                    wsb += (size_t)NBINS * 4;
    int*       binoff   = (int*)wsb;                    wsb += (size_t)(NBINS + 1) * 4;
    int*       rowptr   = (int*)wsb;                    wsb += (size_t)(N_NODES + 1) * 4;
    int*       gstart   = (int*)wsb;                    wsb += (size_t)(N_GRAPHS + 1) * 4;
    float*     colsum   = (float*)wsb;                  wsb += (size_t)3 * EMBED * 4;  // must stay
    float*     colsq    = (float*)wsb;                  wsb += (size_t)3 * EMBED * 4;  // adjacent
    float*     gsum     = (float*)wsb;                  wsb += (size_t)N_GRAPHS * EMBED * 4;
    int*       bar      = (int*)wsb;                    wsb += (size_t)2048 * 4;

    embed_kernel<<<(N_NODES * 16 + 255) / 256, 256, 0, stream>>>(
        nfeat, atom_embed, (float4*)h, hh, gid, gstart, gsum);
    hist2_kernel<<<NSCB, 256, 0, stream>>>(dst, blockhist);
    binreduce_kernel<<<NBINS, NSCB, 0, stream>>>(blockhist, gofs, total);
    binscan_kernel<<<1, 1024, 0, stream>>>(total, binoff, colsum, bar, conv_W, wfrag);
    binscatter_kernel<<<NSCB, 256, 0, stream>>>(src, dst, efeat, binoff, gofs, binned);
    bincsr_kernel<<<NBINS, 256, 0, stream>>>(binned, binoff, rowptr, ebuf);

    for (int i = 0; i < 3; ++i) {
        gather_kernel<<<1536, 256, 0, stream>>>(
            rowptr, ebuf, bond_embed + i * 5 * EMBED, hh, h, (__half*)t16);
        const _Float16* wf = wfrag + (size_t)i * 4096;
        const float* bi = conv_b + (size_t)i * EMBED;
        const float* ga = bn_gamma + (size_t)i * EMBED;
        const float* be = bn_beta + (size_t)i * EMBED;
        float* cs = colsum + (size_t)i * EMBED;
        float* cq = colsq + (size_t)i * EMBED;
        if (i != 2) {
            gemm_bn_fused<<<GB_BLOCKS, 256, 0, stream>>>(
                t16, wf, bi, ga, be, cs, cq, bar + i * 32, h, hh);
        } else {
            gemm_pool_fused<<<GB_BLOCKS, 256, 0, stream>>>(
                t16, wf, bi, ga, be, cs, cq, bar + 2 * 32,
                h, gid, gstart, gsum, pred_W, pred_b, out);
        }
    }
}

// Round 4
// 342.478 us; speedup vs baseline: 1.4502x; 1.1080x over previous
//
#include <hip/hip_runtime.h>
#include <hip/hip_fp16.h>

#define N_NODES 100000
#define N_EDGES 1000000
#define N_GRAPHS 1000
#define EMBED 64
#define OUT_DIM 128
#define BN_EPS 1e-5f
#define NBINS 782                          // dst>>7 -> 128 nodes per bin
#define NSCB 512                           // scatter blocks (fixed edge ranges)
#define EPB ((N_EDGES + NSCB - 1) / NSCB)  // 1954 edges per block
#define NTILES (N_NODES / 16)              // 6250 exact

#define GB_BLOCKS 512                      // fused gemm grid: 2 blocks/CU guaranteed resident
#define GB_WAVES (GB_BLOCKS * 4)           // 2048 waves
#define TPW 4                              // ceil(6250/2048) tiles per wave
#define BAR_STRIDE 4096                    // ints per barrier instance

typedef _Float16 half8 __attribute__((ext_vector_type(8)));
typedef float floatx4 __attribute__((ext_vector_type(4)));

// Software grid barrier v3 (graph-capture-safe).
// R2 lesson: acquire-polling = per-poll cache invalidate -> storm (166us/kernel).
// R3 lesson: the remaining ~40us/barrier was the per-block __threadfence()s
// (buffer_wbl2/buffer_inv per block; 512 exit-invalidates right before the epilogue's
// 38MB of reads). Fences are unnecessary here: ALL cross-barrier data moves through
// device-scope atomics executed at the memory-side coherent point (atomicAdd writers;
// agent-scope atomic-load readers bypass non-coherent L1/L2), and __syncthreads()
// drains vmcnt(0) before arrival [m97 asm], so arrival happens-after the stat atomics.
// v3: fence-free; 2-level tree arrival (8 blocks/leaf x 64 leaves, 128B-spaced counters)
// bounds same-line RMW serialization; single release-store by the final arriver;
// relaxed flag polling with short s_sleep.
// Layout per instance: leaf counters p[g*32] g=0..63, root p[2048], flag p[2080].
__device__ __forceinline__ void grid_barrier(int* p) {
    __syncthreads();   // all waves' pre-barrier vmem (incl. device atomics) drained
    if (threadIdx.x == 0) {
        int old = __hip_atomic_fetch_add(p + ((int)blockIdx.x >> 3) * 32, 1,
                                         __ATOMIC_RELAXED, __HIP_MEMORY_SCOPE_AGENT);
        if (old == 7) {   // last of this leaf group
            int r = __hip_atomic_fetch_add(p + 2048, 1,
                                           __ATOMIC_RELAXED, __HIP_MEMORY_SCOPE_AGENT);
            if (r == 63)  // last leaf -> release the grid
                __hip_atomic_store(p + 2080, 1, __ATOMIC_RELEASE, __HIP_MEMORY_SCOPE_AGENT);
        }
        int spins = 0;
        while (__hip_atomic_load(p + 2080, __ATOMIC_RELAXED, __HIP_MEMORY_SCOPE_AGENT) == 0) {
            __builtin_amdgcn_s_sleep(4);
            if (++spins > (1 << 21)) break;   // ~0.1s failsafe: visible failure beats deadlock
        }
    }
    __syncthreads();
}

// ---------------- one-time structure kernels ----------------

// writes fp32 h and fp16 mirror; builds graph boundaries; zeroes gsum
__global__ void embed_kernel(const int* __restrict__ nfeat,
                             const float* __restrict__ atom_embed,
                             float4* __restrict__ h4,
                             __half* __restrict__ hh,
                             const int* __restrict__ gid,
                             int* __restrict__ gstart,
                             float* __restrict__ gsum) {
    int idx = blockIdx.x * blockDim.x + threadIdx.x;   // one float4 each
    if (idx <= N_NODES) {   // folded gbound
        int cur  = (idx < N_NODES) ? gid[idx] : N_GRAPHS;
        int prev = (idx == 0) ? -1 : gid[idx - 1];
        for (int g = prev + 1; g <= cur; ++g) gstart[g] = idx;
    }
    if (idx < N_GRAPHS * EMBED) gsum[idx] = 0.0f;
    if (idx >= N_NODES * 16) return;
    int v = idx >> 4, q = idx & 15;
    const float4* ae = (const float4*)atom_embed;
    float4 val = ae[nfeat[v] * 16 + q];
    h4[idx] = val;
    __half2 m0 = __floats2half2_rn(val.x, val.y);
    __half2 m1 = __floats2half2_rn(val.z, val.w);
    uint2 packed;
    packed.x = *(unsigned*)&m0;
    packed.y = *(unsigned*)&m1;
    ((uint2*)hh)[idx] = packed;
}

// per-block LDS histogram of its fixed edge range -> blockhist[bin][block]
__global__ void hist2_kernel(const int* __restrict__ dst, int* __restrict__ blockhist) {
    __shared__ int hist[NBINS];
    for (int i = threadIdx.x; i < NBINS; i += 256) hist[i] = 0;
    __syncthreads();
    int b = blockIdx.x;
    int e0 = b * EPB, e1 = min(e0 + EPB, N_EDGES);
    for (int e = e0 + threadIdx.x; e < e1; e += 256)
        atomicAdd(&hist[dst[e] >> 7], 1);
    __syncthreads();
    for (int i = threadIdx.x; i < NBINS; i += 256)
        blockhist[i * NSCB + b] = hist[i];
}

// one block per bin: exclusive scan of its 512 block-counts -> gofs; total per bin
__global__ void binreduce_kernel(const int* __restrict__ blockhist,
                                 int* __restrict__ gofs, int* __restrict__ total) {
    __shared__ int sm[NSCB];
    int bin = blockIdx.x;
    int i = threadIdx.x;   // 0..511
    int orig = blockhist[bin * NSCB + i];
    sm[i] = orig;
    __syncthreads();
    for (int off = 1; off < NSCB; off <<= 1) {
        int val = sm[i];
        if (i >= off) val += sm[i - off];
        __syncthreads();
        sm[i] = val;
        __syncthreads();
    }
    gofs[bin * NSCB + i] = sm[i] - orig;   // exclusive within bin
    if (i == NSCB - 1) total[bin] = sm[i];
}

// scan 782 bin totals -> binoff (exclusive); zeroes BN stats + barrier blocks; packs W frags
__global__ void binscan_kernel(const int* __restrict__ total,
                               int* __restrict__ binoff, float* __restrict__ stats,
                               int* __restrict__ bar,
                               const float* __restrict__ conv_W,
                               _Float16* __restrict__ wfrag) {
    __shared__ int sm[1024];
    int i = threadIdx.x;
    if (i < 6 * EMBED) stats[i] = 0.0f;
    for (int s = i; s < 4 * BAR_STRIDE; s += 1024) bar[s] = 0;   // 4 barrier instances
    // folded wpack: 3 layers x 512 slots
    for (int s = i; s < 3 * 512; s += 1024) {
        int L = s >> 9, slot = s & 511;
        int lane = slot & 63;
        int f = slot >> 6;          // nt*2+kh
        int nt = f >> 1, kh = f & 1;
        int n  = nt * 16 + (lane & 15);
        int k0 = kh * 32 + (lane >> 4) * 8;
        const float* W = conv_W + L * 4096;
        _Float16* out = wfrag + L * 4096;
#pragma unroll
        for (int j = 0; j < 8; ++j)
            out[slot * 8 + j] = (_Float16)W[(k0 + j) * 64 + n];
    }
    int orig = (i < NBINS) ? total[i] : 0;
    sm[i] = orig;
    __syncthreads();
    for (int off = 1; off < 1024; off <<= 1) {
        int val = sm[i];
        if (i >= off) val += sm[i - off];
        __syncthreads();
        sm[i] = val;
        __syncthreads();
    }
    if (i < NBINS) binoff[i] = sm[i] - orig;
    if (i == 0) binoff[NBINS] = N_EDGES;
}

// deterministic multisplit scatter: LDS cursors seeded from binoff+gofs.
__global__ void binscatter_kernel(const int* __restrict__ src, const int* __restrict__ dst,
                                  const int* __restrict__ efeat,
                                  const int* __restrict__ binoff, const int* __restrict__ gofs,
                                  unsigned* __restrict__ binned) {
    __shared__ int cur[NBINS];
    int b = blockIdx.x;
    for (int i = threadIdx.x; i < NBINS; i += 256)
        cur[i] = binoff[i] + gofs[i * NSCB + b];
    __syncthreads();
    int e0 = b * EPB, e1 = min(e0 + EPB, N_EDGES);
    for (int e = e0 + threadIdx.x; e < e1; e += 256) {
        int t = dst[e];
        int bin = t >> 7;
        int pos = atomicAdd(&cur[bin], 1);   // LDS atomic
        binned[pos] = (unsigned)src[e] | ((unsigned)efeat[e] << 17)
                    | ((unsigned)(t & 127) << 20);
    }
}

// one block per bin: local deg count + local scan -> rowptr slice + ebuf region
__global__ void bincsr_kernel(const unsigned* __restrict__ binned,
                              const int* __restrict__ binoff,
                              int* __restrict__ rowptr,
                              unsigned* __restrict__ ebuf) {
    __shared__ int cnt[128];
    __shared__ int sc[128];
    int b = blockIdx.x;
    int tid = threadIdx.x;
    int base = binoff[b], end = binoff[b + 1];

    if (tid < 128) cnt[tid] = 0;
    __syncthreads();

    for (int i = base + tid; i < end; i += 256)
        atomicAdd(&cnt[binned[i] >> 20], 1);
    __syncthreads();

    if (tid < 128) sc[tid] = cnt[tid];
    __syncthreads();
    for (int off = 1; off < 128; off <<= 1) {
        int val = 0;
        if (tid < 128) {
            val = sc[tid];
            if (tid >= off) val += sc[tid - off];
        }
        __syncthreads();
        if (tid < 128) sc[tid] = val;
        __syncthreads();
    }
    if (tid < 128) {
        int excl = sc[tid] - cnt[tid];
        int v = b * 128 + tid;
        if (v < N_NODES) rowptr[v] = base + excl;
        cnt[tid] = excl;   // becomes running cursor
    }
    if (b == 0 && tid == 255) rowptr[N_NODES] = N_EDGES;
    __syncthreads();

    for (int i = base + tid; i < end; i += 256) {
        unsigned rec = binned[i];
        int dl = rec >> 20;
        int pos = base + atomicAdd(&cnt[dl], 1);
        ebuf[pos] = (rec & 0x1FFFFu) | (((rec >> 17) & 0x7u) << 20);
    }
}

// ---------------- per-layer kernels ----------------

// Gather: quarter-wave per node. At the random-line service-rate wall (R6/R10/R18).
__launch_bounds__(256, 6)
__global__ void gather_kernel(const int* __restrict__ rowptr,
                              const unsigned* __restrict__ ebuf,
                              const float* __restrict__ bond,    // [5,64]
                              const __half* __restrict__ hh,     // fp16 mirror
                              const float* __restrict__ hmast,   // fp32 master
                              __half* __restrict__ t16) {
    __shared__ float bond_s[5 * EMBED];
    for (int i = threadIdx.x; i < 5 * EMBED; i += 256) bond_s[i] = bond[i];
    __syncthreads();

    int sl = threadIdx.x & 15;    // uint2 slot: dims 4sl..4sl+3
    int d0 = sl * 4;
    int gq = (blockIdx.x * 256 + threadIdx.x) >> 4;   // global quarter id
    int nq = (gridDim.x * 256) >> 4;
    const uint2* hhq = (const uint2*)hh;    // 16 uint2 per node row

    for (int v = gq; v < N_NODES; v += nq) {
        int rb = rowptr[v], re = rowptr[v + 1];
        float4 a0 = {0,0,0,0}, a1 = {0,0,0,0}, a2 = {0,0,0,0}, a3 = {0,0,0,0};
        int e = rb;
        for (; e + 4 <= re; e += 4) {
            unsigned p0 = ebuf[e + 0];
            unsigned p1 = ebuf[e + 1];
            unsigned p2 = ebuf[e + 2];
            unsigned p3 = ebuf[e + 3];
            uint2 g0 = hhq[(size_t)(p0 & 0xFFFFFu) * 16 + sl];
            uint2 g1 = hhq[(size_t)(p1 & 0xFFFFFu) * 16 + sl];
            uint2 g2 = hhq[(size_t)(p2 & 0xFFFFFu) * 16 + sl];
            uint2 g3 = hhq[(size_t)(p3 & 0xFFFFFu) * 16 + sl];
            const float* c0 = &bond_s[(p0 >> 20) * EMBED + d0];
            const float* c1 = &bond_s[(p1 >> 20) * EMBED + d0];
            const float* c2 = &bond_s[(p2 >> 20) * EMBED + d0];
            const float* c3 = &bond_s[(p3 >> 20) * EMBED + d0];
            float2 f0a = __half22float2(*(const __half2*)&g0.x);
            float2 f0b = __half22float2(*(const __half2*)&g0.y);
            float2 f1a = __half22float2(*(const __half2*)&g1.x);
            float2 f1b = __half22float2(*(const __half2*)&g1.y);
            float2 f2a = __half22float2(*(const __half2*)&g2.x);
            float2 f2b = __half22float2(*(const __half2*)&g2.y);
            float2 f3a = __half22float2(*(const __half2*)&g3.x);
            float2 f3b = __half22float2(*(const __half2*)&g3.y);
            a0.x += fmaxf(f0a.x + c0[0], 0.f); a0.y += fmaxf(f0a.y + c0[1], 0.f);
            a0.z += fmaxf(f0b.x + c0[2], 0.f); a0.w += fmaxf(f0b.y + c0[3], 0.f);
            a1.x += fmaxf(f1a.x + c1[0], 0.f); a1.y += fmaxf(f1a.y + c1[1], 0.f);
            a1.z += fmaxf(f1b.x + c1[2], 0.f); a1.w += fmaxf(f1b.y + c1[3], 0.f);
            a2.x += fmaxf(f2a.x + c2[0], 0.f); a2.y += fmaxf(f2a.y + c2[1], 0.f);
            a2.z += fmaxf(f2b.x + c2[2], 0.f); a2.w += fmaxf(f2b.y + c2[3], 0.f);
            a3.x += fmaxf(f3a.x + c3[0], 0.f); a3.y += fmaxf(f3a.y + c3[1], 0.f);
            a3.z += fmaxf(f3b.x + c3[2], 0.f); a3.w += fmaxf(f3b.y + c3[3], 0.f);
        }
        for (; e < re; ++e) {
            unsigned p = ebuf[e];
            uint2 g = hhq[(size_t)(p & 0xFFFFFu) * 16 + sl];
            const float* c = &bond_s[(p >> 20) * EMBED + d0];
            float2 fa = __half22float2(*(const __half2*)&g.x);
            float2 fb = __half22float2(*(const __half2*)&g.y);
            a0.x += fmaxf(fa.x + c[0], 0.f); a0.y += fmaxf(fa.y + c[1], 0.f);
            a0.z += fmaxf(fb.x + c[2], 0.f); a0.w += fmaxf(fb.y + c[3], 0.f);
        }
        float inv = 1.0f / fmaxf((float)(re - rb), 1.0f);
        float4 hr = ((const float4*)hmast)[(size_t)v * 16 + sl];
        float tx = (a0.x + a1.x + a2.x + a3.x) * inv + hr.x;
        float ty = (a0.y + a1.y + a2.y + a3.y) * inv + hr.y;
        float tz = (a0.z + a1.z + a2.z + a3.z) * inv + hr.z;
        float tw = (a0.w + a1.w + a2.w + a3.w) * inv + hr.w;
        __half2 m0 = __floats2half2_rn(tx, ty);
        __half2 m1 = __floats2half2_rn(tz, tw);
        uint2 packed;
        packed.x = *(unsigned*)&m0;
        packed.y = *(unsigned*)&m1;
        ((uint2*)t16)[(size_t)v * 16 + sl] = packed;
    }
}

// Fused GEMM + BN stats + grid barrier + BN/relu/residual (layers 0,1).
// MFMA accumulators stay in registers across the barrier: h_pre16 round-trip removed.
// C/D layout: col=lane&15, row=(lane>>4)*4+reg [m89].
__launch_bounds__(256, 2)
__global__ void gemm_bn_fused(const _Float16* __restrict__ t16,
                              const _Float16* __restrict__ wfrag,  // packed
                              const float* __restrict__ bias,
                              const float* __restrict__ gamma,
                              const float* __restrict__ beta,
                              float* __restrict__ colsum,
                              float* __restrict__ colsq,
                              int* __restrict__ bar,
                              float* __restrict__ h,      // fp32 master (in: residual, out: new h)
                              __half* __restrict__ hh) {  // fp16 mirror out
    __shared__ float red[4][8][16];
    __shared__ float sscale[EMBED];
    __shared__ float sshift[EMBED];

    int lane = threadIdx.x & 63;
    int wblk = threadIdx.x >> 6;
    int quad = lane >> 4;
    int col  = lane & 15;
    int wid  = blockIdx.x * 4 + wblk;

    half8 bf[4][2];
#pragma unroll
    for (int nt = 0; nt < 4; ++nt)
#pragma unroll
        for (int kh = 0; kh < 2; ++kh)
            bf[nt][kh] = *(const half8*)(wfrag + ((size_t)(nt * 2 + kh) * 64 + lane) * 8);

    float bj[4];
#pragma unroll
    for (int nt = 0; nt < 4; ++nt) bj[nt] = bias[nt * 16 + col];

    float lsum[4] = {0.f, 0.f, 0.f, 0.f};
    float lsq [4] = {0.f, 0.f, 0.f, 0.f};
    floatx4 c[TPW][4];

#pragma unroll
    for (int k = 0; k < TPW; ++k) {
        int tile = wid + k * GB_WAVES;
        if (tile >= NTILES) continue;
        int base = tile * 16;
        const _Float16* arow = t16 + (size_t)(base + col) * 64 + quad * 8;
        half8 a0 = *(const half8*)(arow);
        half8 a1 = *(const half8*)(arow + 32);
#pragma unroll
        for (int nt = 0; nt < 4; ++nt) {
            floatx4 cc = {bj[nt], bj[nt], bj[nt], bj[nt]};
            cc = __builtin_amdgcn_mfma_f32_16x16x32_f16(a0, bf[nt][0], cc, 0, 0, 0);
            cc = __builtin_amdgcn_mfma_f32_16x16x32_f16(a1, bf[nt][1], cc, 0, 0, 0);
            c[k][nt] = cc;
#pragma unroll
            for (int r = 0; r < 4; ++r) {
                float v = cc[r];
                lsum[nt] += v;
                lsq[nt]  += v * v;
            }
        }
    }

#pragma unroll
    for (int nt = 0; nt < 4; ++nt) {
        lsum[nt] += __shfl_xor(lsum[nt], 16); lsum[nt] += __shfl_xor(lsum[nt], 32);
        lsq[nt]  += __shfl_xor(lsq[nt], 16);  lsq[nt]  += __shfl_xor(lsq[nt], 32);
    }
    if (lane < 16) {
#pragma unroll
        for (int nt = 0; nt < 4; ++nt) {
            red[wblk][nt * 2 + 0][lane] = lsum[nt];
            red[wblk][nt * 2 + 1][lane] = lsq[nt];
        }
    }
    __syncthreads();
    if (threadIdx.x < 128) {
        int f = threadIdx.x >> 4, l = threadIdx.x & 15;
        float s = red[0][f][l] + red[1][f][l] + red[2][f][l] + red[3][f][l];
        int nt = f >> 1;
        if ((f & 1) == 0) atomicAdd(&colsum[nt * 16 + l], s);
        else              atomicAdd(&colsq[nt * 16 + l], s);
    }

    grid_barrier(bar);

    // stats -> scale/shift once per block
    if (threadIdx.x < EMBED) {
        int j = threadIdx.x;
        const float invN = 1.0f / (float)N_NODES;
        float s = __hip_atomic_load(&colsum[j], __ATOMIC_RELAXED, __HIP_MEMORY_SCOPE_AGENT);
        float q = __hip_atomic_load(&colsq[j],  __ATOMIC_RELAXED, __HIP_MEMORY_SCOPE_AGENT);
        float mu  = s * invN;
        float var = q * invN - mu * mu;
        float scv = rsqrtf(var + BN_EPS) * gamma[j];
        sscale[j] = scv;
        sshift[j] = beta[j] - mu * scv;
    }
    __syncthreads();

    float scr[4], shr[4];
#pragma unroll
    for (int nt = 0; nt < 4; ++nt) {
        scr[nt] = sscale[nt * 16 + col];
        shr[nt] = sshift[nt * 16 + col];
    }

#pragma unroll
    for (int k = 0; k < TPW; ++k) {
        int tile = wid + k * GB_WAVES;
        if (tile >= NTILES) continue;
        int base = tile * 16;
#pragma unroll
        for (int nt = 0; nt < 4; ++nt) {
#pragma unroll
            for (int r = 0; r < 4; ++r) {
                int node = base + quad * 4 + r;
                size_t off = (size_t)node * EMBED + nt * 16 + col;
                float y = fmaxf(c[k][nt][r] * scr[nt] + shr[nt], 0.0f);  // layers 0,1 relu
                float o = y + h[off];                                    // residual
                h[off] = o;
                hh[off] = __float2half(o);
            }
        }
    }
}

// Fused layer-2 GEMM + BN stats + barrier + BN/residual/graph-pool + barrier + pred.
// Final h never materialized. Pool exploits sorted graph_ids: tile-uniform graphs take
// one wave-reduced atomic per (nt,col); boundary tiles fall back to per-row atomics.
__launch_bounds__(256, 2)
__global__ void gemm_pool_fused(const _Float16* __restrict__ t16,
                                const _Float16* __restrict__ wfrag,
                                const float* __restrict__ bias,
                                const float* __restrict__ gamma,
                                const float* __restrict__ beta,
                                float* __restrict__ colsum,
                                float* __restrict__ colsq,
                                int* __restrict__ bar,       // two instances: bar, bar+BAR_STRIDE
                                const float* __restrict__ h, // residual (layer-1 output)
                                const int* __restrict__ gid,
                                const int* __restrict__ gstart,
                                float* __restrict__ gsum,    // [N_GRAPHS, EMBED] zeroed
                                const float* __restrict__ predW, // [64,128]
                                const float* __restrict__ predb, // [128]
                                float* __restrict__ out) {       // [G, OUT_DIM]
    __shared__ float red[4][8][16];
    __shared__ float sscale[EMBED];
    __shared__ float sshift[EMBED];
    __shared__ float gm[EMBED];

    int lane = threadIdx.x & 63;
    int wblk = threadIdx.x >> 6;
    int quad = lane >> 4;
    int col  = lane & 15;
    int wid  = blockIdx.x * 4 + wblk;

    half8 bf[4][2];
#pragma unroll
    for (int nt = 0; nt < 4; ++nt)
#pragma unroll
        for (int kh = 0; kh < 2; ++kh)
            bf[nt][kh] = *(const half8*)(wfrag + ((size_t)(nt * 2 + kh) * 64 + lane) * 8);

    float bj[4];
#pragma unroll
    for (int nt = 0; nt < 4; ++nt) bj[nt] = bias[nt * 16 + col];

    float lsum[4] = {0.f, 0.f, 0.f, 0.f};
    float lsq [4] = {0.f, 0.f, 0.f, 0.f};
    floatx4 c[TPW][4];

#pragma unroll
    for (int k = 0; k < TPW; ++k) {
        int tile = wid + k * GB_WAVES;
        if (tile >= NTILES) continue;
        int base = tile * 16;
        const _Float16* arow = t16 + (size_t)(base + col) * 64 + quad * 8;
        half8 a0 = *(const half8*)(arow);
        half8 a1 = *(const half8*)(arow + 32);
#pragma unroll
        for (int nt = 0; nt < 4; ++nt) {
            floatx4 cc = {bj[nt], bj[nt], bj[nt], bj[nt]};
            cc = __builtin_amdgcn_mfma_f32_16x16x32_f16(a0, bf[nt][0], cc, 0, 0, 0);
            cc = __builtin_amdgcn_mfma_f32_16x16x32_f16(a1, bf[nt][1], cc, 0, 0, 0);
            c[k][nt] = cc;
#pragma unroll
            for (int r = 0; r < 4; ++r) {
                float v = cc[r];
                lsum[nt] += v;
                lsq[nt]  += v * v;
            }
        }
    }

#pragma unroll
    for (int nt = 0; nt < 4; ++nt) {
        lsum[nt] += __shfl_xor(lsum[nt], 16); lsum[nt] += __shfl_xor(lsum[nt], 32);
        lsq[nt]  += __shfl_xor(lsq[nt], 16);  lsq[nt]  += __shfl_xor(lsq[nt], 32);
    }
    if (lane < 16) {
#pragma unroll
        for (int nt = 0; nt < 4; ++nt) {
            red[wblk][nt * 2 + 0][lane] = lsum[nt];
            red[wblk][nt * 2 + 1][lane] = lsq[nt];
        }
    }
    __syncthreads();
    if (threadIdx.x < 128) {
        int f = threadIdx.x >> 4, l = threadIdx.x & 15;
        float s = red[0][f][l] + red[1][f][l] + red[2][f][l] + red[3][f][l];
        int nt = f >> 1;
        if ((f & 1) == 0) atomicAdd(&colsum[nt * 16 + l], s);
        else              atomicAdd(&colsq[nt * 16 + l], s);
    }

    grid_barrier(bar);

    if (threadIdx.x < EMBED) {
        int j = threadIdx.x;
        const float invN = 1.0f / (float)N_NODES;
        float s = __hip_atomic_load(&colsum[j], __ATOMIC_RELAXED, __HIP_MEMORY_SCOPE_AGENT);
        float q = __hip_atomic_load(&colsq[j],  __ATOMIC_RELAXED, __HIP_MEMORY_SCOPE_AGENT);
        float mu  = s * invN;
        float var = q * invN - mu * mu;
        float scv = rsqrtf(var + BN_EPS) * gamma[j];   // no relu on last layer
        sscale[j] = scv;
        sshift[j] = beta[j] - mu * scv;
    }
    __syncthreads();

    float scr[4], shr[4];
#pragma unroll
    for (int nt = 0; nt < 4; ++nt) {
        scr[nt] = sscale[nt * 16 + col];
        shr[nt] = sshift[nt * 16 + col];
    }

#pragma unroll
    for (int k = 0; k < TPW; ++k) {
        int tile = wid + k * GB_WAVES;
        if (tile >= NTILES) continue;
        int base = tile * 16;
        int g0  = gid[base];
        int g15 = gid[base + 15];
        float val[4][4];   // [nt][r]
#pragma unroll
        for (int r = 0; r < 4; ++r) {
            int node = base + quad * 4 + r;
#pragma unroll
            for (int nt = 0; nt < 4; ++nt) {
                size_t off = (size_t)node * EMBED + nt * 16 + col;
                val[nt][r] = c[k][nt][r] * scr[nt] + shr[nt] + h[off];
            }
        }
        if (g0 == g15) {   // gid sorted -> whole tile is one graph (wave-uniform branch)
#pragma unroll
            for (int nt = 0; nt < 4; ++nt) {
                float s = val[nt][0] + val[nt][1] + val[nt][2] + val[nt][3];
                s += __shfl_xor(s, 16);
                s += __shfl_xor(s, 32);
                if (quad == 0)
                    atomicAdd(&gsum[(size_t)g0 * EMBED + nt * 16 + col], s);
            }
        } else {
#pragma unroll
            for (int r = 0; r < 4; ++r) {
                int node = base + quad * 4 + r;
                int g = gid[node];
#pragma unroll
                for (int nt = 0; nt < 4; ++nt)
                    atomicAdd(&gsum[(size_t)g * EMBED + nt * 16 + col], val[nt][r]);
            }
        }
    }

    grid_barrier(bar + BAR_STRIDE);

    // pred: block per graph (grid-strided), gm row via LDS, 128 outputs
    for (int g = blockIdx.x; g < N_GRAPHS; g += gridDim.x) {
        int nb = gstart[g], ne = gstart[g + 1];
        float invc = 1.0f / fmaxf((float)(ne - nb), 1.0f);
        if (threadIdx.x < EMBED)
            gm[threadIdx.x] = __hip_atomic_load(&gsum[(size_t)g * EMBED + threadIdx.x],
                                                __ATOMIC_RELAXED, __HIP_MEMORY_SCOPE_AGENT) * invc;
        __syncthreads();
        if (threadIdx.x < OUT_DIM) {
            float acc = predb[threadIdx.x];
#pragma unroll
            for (int d = 0; d < EMBED; ++d)
                acc += gm[d] * predW[d * OUT_DIM + threadIdx.x];
            out[g * OUT_DIM + threadIdx.x] = acc;
        }
        __syncthreads();
    }
}

// ---------------- launch ----------------

extern "C" void kernel_launch(void* const* d_in, const int* in_sizes, int n_in,
                              void* d_out, int out_size, void* d_ws, size_t ws_size,
                              hipStream_t stream) {
    const int*   nfeat      = (const int*)d_in[0];
    const int*   efeat      = (const int*)d_in[1];
    const int*   src        = (const int*)d_in[2];
    const int*   dst        = (const int*)d_in[3];
    const int*   gid        = (const int*)d_in[4];
    const float* atom_embed = (const float*)d_in[5];
    const float* bond_embed = (const float*)d_in[6];  // [3,5,64]
    const float* conv_W     = (const float*)d_in[7];  // [3,64,64]
    const float* conv_b     = (const float*)d_in[8];  // [3,64]
    const float* bn_gamma   = (const float*)d_in[9];  // [3,64]
    const float* bn_beta    = (const float*)d_in[10]; // [3,64]
    const float* pred_W     = (const float*)d_in[11]; // [64,128]
    const float* pred_b     = (const float*)d_in[12]; // [128]
    float* out = (float*)d_out;

    char* wsb = (char*)d_ws;
    float*     h        = (float*)wsb;                  wsb += (size_t)N_NODES * EMBED * 4;
    _Float16*  t16      = (_Float16*)wsb;               wsb += (size_t)N_NODES * EMBED * 2;
    __half*    hh       = (__half*)wsb;                 wsb += (size_t)N_NODES * EMBED * 2;
    _Float16*  wfrag    = (_Float16*)wsb;               wsb += (size_t)3 * 4096 * 2;
    unsigned*  binned   = (unsigned*)wsb;               wsb += (size_t)N_EDGES * 4;
    unsigned*  ebuf     = (unsigned*)wsb;               wsb += (size_t)N_EDGES * 4;
    int*       blockhist= (int*)wsb;                    wsb += (size_t)NBINS * NSCB * 4;
    int*       gofs     = (int*)wsb;                    wsb += (size_t)NBINS * NSCB * 4;
    int*       total    = (int*)wsb;                    wsb += (size_t)NBINS * 4;
    int*       binoff   = (int*)wsb;                    wsb += (size_t)(NBINS + 1) * 4;
    int*       rowptr   = (int*)wsb;                    wsb += (size_t)(N_NODES + 1) * 4;
    int*       gstart   = (int*)wsb;                    wsb += (size_t)(N_GRAPHS + 1) * 4;
    float*     colsum   = (float*)wsb;                  wsb += (size_t)3 * EMBED * 4;  // must stay
    float*     colsq    = (float*)wsb;                  wsb += (size_t)3 * EMBED * 4;  // adjacent
    float*     gsum     = (float*)wsb;                  wsb += (size_t)N_GRAPHS * EMBED * 4;
    int*       bar      = (int*)wsb;                    wsb += (size_t)4 * BAR_STRIDE * 4;

    embed_kernel<<<(N_NODES * 16 + 255) / 256, 256, 0, stream>>>(
        nfeat, atom_embed, (float4*)h, hh, gid, gstart, gsum);
    hist2_kernel<<<NSCB, 256, 0, stream>>>(dst, blockhist);
    binreduce_kernel<<<NBINS, NSCB, 0, stream>>>(blockhist, gofs, total);
    binscan_kernel<<<1, 1024, 0, stream>>>(total, binoff, colsum, bar, conv_W, wfrag);
    binscatter_kernel<<<NSCB, 256, 0, stream>>>(src, dst, efeat, binoff, gofs, binned);
    bincsr_kernel<<<NBINS, 256, 0, stream>>>(binned, binoff, rowptr, ebuf);

    for (int i = 0; i < 3; ++i) {
        gather_kernel<<<1536, 256, 0, stream>>>(
            rowptr, ebuf, bond_embed + i * 5 * EMBED, hh, h, (__half*)t16);
        const _Float16* wf = wfrag + (size_t)i * 4096;
        const float* bi = conv_b + (size_t)i * EMBED;
        const float* ga = bn_gamma + (size_t)i * EMBED;
        const float* be = bn_beta + (size_t)i * EMBED;
        float* cs = colsum + (size_t)i * EMBED;
        float* cq = colsq + (size_t)i * EMBED;
        if (i != 2) {
            gemm_bn_fused<<<GB_BLOCKS, 256, 0, stream>>>(
                t16, wf, bi, ga, be, cs, cq, bar + (size_t)i * BAR_STRIDE, h, hh);
        } else {
            gemm_pool_fused<<<GB_BLOCKS, 256, 0, stream>>>(
                t16, wf, bi, ga, be, cs, cq, bar + (size_t)2 * BAR_STRIDE,
                h, gid, gstart, gsum, pred_W, pred_b, out);
        }
    }
}

// Round 6
// 342.066 us; speedup vs baseline: 1.4519x; 1.0012x over previous
//
#include <hip/hip_runtime.h>
#include <hip/hip_fp16.h>

#define N_NODES 100000
#define N_EDGES 1000000
#define N_GRAPHS 1000
#define EMBED 64
#define OUT_DIM 128
#define BN_EPS 1e-5f
#define NBINS 782                          // dst>>7 -> 128 nodes per bin
#define NSCB 512                           // scatter blocks (fixed edge ranges)
#define EPB ((N_EDGES + NSCB - 1) / NSCB)  // 1954 edges per block
#define NTILES (N_NODES / 16)              // 6250 exact

#define GB_BLOCKS 512                      // fused gemm grid: 2 blocks/CU guaranteed resident
#define GB_WAVES (GB_BLOCKS * 4)           // 2048 waves
#define TPW 4                              // ceil(6250/2048) tiles per wave
#define BAR_STRIDE 8192                    // ints per barrier instance

typedef _Float16 half8 __attribute__((ext_vector_type(8)));
typedef float floatx4 __attribute__((ext_vector_type(4)));

// Software grid barrier v4 (graph-capture-safe).
// R2: acquire-polling = per-poll invalidate storm (166us). R3: per-block threadfences
// (wbl2/inv bursts) ~40us. R4: remaining ~19us/barrier = two single-line herds:
// 512 pollers on ONE flag line + 512 blocks' agent-atomic reads of the SAME stat lines
// at release (same-line serialization at the coherent point).
// v4: tree ARRIVAL (64 leaves x 8, 128B apart) + tree RELEASE (last arriver writes 64
// leaf flags; only 8 pollers per flag line). All RELAXED: happens-before is carried by
// completed coherent-point RMWs (__syncthreads drains vmcnt -> every block's stats
// atomics completed before its arrival add; releaser's root RMW completed before flag
// stores issue). Post-barrier stat reads use PLAIN loads: kernel-start acquire has
// invalidated L1/L2 and nothing read those lines pre-barrier in this kernel, so there is
// no stale copy; L2 then serves the within-XCD broadcast instead of the coherent point.
// asm "memory" fences = COMPILER-ONLY ordering (no cache ops emitted): pin the stat
// loads below the flag observation and the stat atomics above the arrival add.
// Layout per instance: leaf counters p[g*32] g=0..63; root p[2048]; flags p[2080+g*32].
__device__ __forceinline__ void grid_barrier(int* p) {
    __syncthreads();   // all waves' pre-barrier vmem (incl. device atomics) drained
    if (threadIdx.x == 0) {
        asm volatile("" ::: "memory");
        int leaf = (int)blockIdx.x >> 3;
        int old = __hip_atomic_fetch_add(p + leaf * 32, 1,
                                         __ATOMIC_RELAXED, __HIP_MEMORY_SCOPE_AGENT);
        if (old == 7) {   // last of this leaf group
            int r = __hip_atomic_fetch_add(p + 2048, 1,
                                           __ATOMIC_RELAXED, __HIP_MEMORY_SCOPE_AGENT);
            if (r == 63) {  // last leaf -> fan-out release
                for (int g = 0; g < 64; ++g)
                    __hip_atomic_store(p + 2080 + g * 32, 1,
                                       __ATOMIC_RELAXED, __HIP_MEMORY_SCOPE_AGENT);
            }
        }
        int spins = 0;
        while (__hip_atomic_load(p + 2080 + leaf * 32,
                                 __ATOMIC_RELAXED, __HIP_MEMORY_SCOPE_AGENT) == 0) {
            __builtin_amdgcn_s_sleep(8);
            if (++spins > (1 << 17)) break;   // ~25ms failsafe: fail visibly, never wedge
        }
        asm volatile("" ::: "memory");
    }
    __syncthreads();
}

// ---------------- one-time structure kernels ----------------

// writes fp32 h and fp16 mirror; builds graph boundaries; zeroes gsum
__global__ void embed_kernel(const int* __restrict__ nfeat,
                             const float* __restrict__ atom_embed,
                             float4* __restrict__ h4,
                             __half* __restrict__ hh,
                             const int* __restrict__ gid,
                             int* __restrict__ gstart,
                             float* __restrict__ gsum) {
    int idx = blockIdx.x * blockDim.x + threadIdx.x;   // one float4 each
    if (idx <= N_NODES) {   // folded gbound
        int cur  = (idx < N_NODES) ? gid[idx] : N_GRAPHS;
        int prev = (idx == 0) ? -1 : gid[idx - 1];
        for (int g = prev + 1; g <= cur; ++g) gstart[g] = idx;
    }
    if (idx < N_GRAPHS * EMBED) gsum[idx] = 0.0f;
    if (idx >= N_NODES * 16) return;
    int v = idx >> 4, q = idx & 15;
    const float4* ae = (const float4*)atom_embed;
    float4 val = ae[nfeat[v] * 16 + q];
    h4[idx] = val;
    __half2 m0 = __floats2half2_rn(val.x, val.y);
    __half2 m1 = __floats2half2_rn(val.z, val.w);
    uint2 packed;
    packed.x = *(unsigned*)&m0;
    packed.y = *(unsigned*)&m1;
    ((uint2*)hh)[idx] = packed;
}

// per-block LDS histogram of its fixed edge range -> blockhist[bin][block]
__global__ void hist2_kernel(const int* __restrict__ dst, int* __restrict__ blockhist) {
    __shared__ int hist[NBINS];
    for (int i = threadIdx.x; i < NBINS; i += 256) hist[i] = 0;
    __syncthreads();
    int b = blockIdx.x;
    int e0 = b * EPB, e1 = min(e0 + EPB, N_EDGES);
    for (int e = e0 + threadIdx.x; e < e1; e += 256)
        atomicAdd(&hist[dst[e] >> 7], 1);
    __syncthreads();
    for (int i = threadIdx.x; i < NBINS; i += 256)
        blockhist[i * NSCB + b] = hist[i];
}

// one block per bin: exclusive scan of its 512 block-counts -> gofs; total per bin
__global__ void binreduce_kernel(const int* __restrict__ blockhist,
                                 int* __restrict__ gofs, int* __restrict__ total) {
    __shared__ int sm[NSCB];
    int bin = blockIdx.x;
    int i = threadIdx.x;   // 0..511
    int orig = blockhist[bin * NSCB + i];
    sm[i] = orig;
    __syncthreads();
    for (int off = 1; off < NSCB; off <<= 1) {
        int val = sm[i];
        if (i >= off) val += sm[i - off];
        __syncthreads();
        sm[i] = val;
        __syncthreads();
    }
    gofs[bin * NSCB + i] = sm[i] - orig;   // exclusive within bin
    if (i == NSCB - 1) total[bin] = sm[i];
}

// scan 782 bin totals -> binoff (exclusive); zeroes BN stats + barrier blocks; packs W frags
__global__ void binscan_kernel(const int* __restrict__ total,
                               int* __restrict__ binoff, float* __restrict__ stats,
                               int* __restrict__ bar,
                               const float* __restrict__ conv_W,
                               _Float16* __restrict__ wfrag) {
    __shared__ int sm[1024];
    int i = threadIdx.x;
    if (i < 6 * EMBED) stats[i] = 0.0f;
    for (int s = i; s < 4 * BAR_STRIDE; s += 1024) bar[s] = 0;   // 4 barrier instances
    // folded wpack: 3 layers x 512 slots
    for (int s = i; s < 3 * 512; s += 1024) {
        int L = s >> 9, slot = s & 511;
        int lane = slot & 63;
        int f = slot >> 6;          // nt*2+kh
        int nt = f >> 1, kh = f & 1;
        int n  = nt * 16 + (lane & 15);
        int k0 = kh * 32 + (lane >> 4) * 8;
        const float* W = conv_W + L * 4096;
        _Float16* out = wfrag + L * 4096;
#pragma unroll
        for (int j = 0; j < 8; ++j)
            out[slot * 8 + j] = (_Float16)W[(k0 + j) * 64 + n];
    }
    int orig = (i < NBINS) ? total[i] : 0;
    sm[i] = orig;
    __syncthreads();
    for (int off = 1; off < 1024; off <<= 1) {
        int val = sm[i];
        if (i >= off) val += sm[i - off];
        __syncthreads();
        sm[i] = val;
        __syncthreads();
    }
    if (i < NBINS) binoff[i] = sm[i] - orig;
    if (i == 0) binoff[NBINS] = N_EDGES;
}

// deterministic multisplit scatter: LDS cursors seeded from binoff+gofs.
__global__ void binscatter_kernel(const int* __restrict__ src, const int* __restrict__ dst,
                                  const int* __restrict__ efeat,
                                  const int* __restrict__ binoff, const int* __restrict__ gofs,
                                  unsigned* __restrict__ binned) {
    __shared__ int cur[NBINS];
    int b = blockIdx.x;
    for (int i = threadIdx.x; i < NBINS; i += 256)
        cur[i] = binoff[i] + gofs[i * NSCB + b];
    __syncthreads();
    int e0 = b * EPB, e1 = min(e0 + EPB, N_EDGES);
    for (int e = e0 + threadIdx.x; e < e1; e += 256) {
        int t = dst[e];
        int bin = t >> 7;
        int pos = atomicAdd(&cur[bin], 1);   // LDS atomic
        binned[pos] = (unsigned)src[e] | ((unsigned)efeat[e] << 17)
                    | ((unsigned)(t & 127) << 20);
    }
}

// one block per bin: local deg count + local scan -> rowptr slice + ebuf region
__global__ void bincsr_kernel(const unsigned* __restrict__ binned,
                              const int* __restrict__ binoff,
                              int* __restrict__ rowptr,
                              unsigned* __restrict__ ebuf) {
    __shared__ int cnt[128];
    __shared__ int sc[128];
    int b = blockIdx.x;
    int tid = threadIdx.x;
    int base = binoff[b], end = binoff[b + 1];

    if (tid < 128) cnt[tid] = 0;
    __syncthreads();

    for (int i = base + tid; i < end; i += 256)
        atomicAdd(&cnt[binned[i] >> 20], 1);
    __syncthreads();

    if (tid < 128) sc[tid] = cnt[tid];
    __syncthreads();
    for (int off = 1; off < 128; off <<= 1) {
        int val = 0;
        if (tid < 128) {
            val = sc[tid];
            if (tid >= off) val += sc[tid - off];
        }
        __syncthreads();
        if (tid < 128) sc[tid] = val;
        __syncthreads();
    }
    if (tid < 128) {
        int excl = sc[tid] - cnt[tid];
        int v = b * 128 + tid;
        if (v < N_NODES) rowptr[v] = base + excl;
        cnt[tid] = excl;   // becomes running cursor
    }
    if (b == 0 && tid == 255) rowptr[N_NODES] = N_EDGES;
    __syncthreads();

    for (int i = base + tid; i < end; i += 256) {
        unsigned rec = binned[i];
        int dl = rec >> 20;
        int pos = base + atomicAdd(&cnt[dl], 1);
        ebuf[pos] = (rec & 0x1FFFFu) | (((rec >> 17) & 0x7u) << 20);
    }
}

// ---------------- per-layer kernels ----------------

// Gather: quarter-wave per node. At the random-line service-rate wall (R6/R10/R18).
__launch_bounds__(256, 6)
__global__ void gather_kernel(const int* __restrict__ rowptr,
                              const unsigned* __restrict__ ebuf,
                              const float* __restrict__ bond,    // [5,64]
                              const __half* __restrict__ hh,     // fp16 mirror
                              const float* __restrict__ hmast,   // fp32 master
                              __half* __restrict__ t16) {
    __shared__ float bond_s[5 * EMBED];
    for (int i = threadIdx.x; i < 5 * EMBED; i += 256) bond_s[i] = bond[i];
    __syncthreads();

    int sl = threadIdx.x & 15;    // uint2 slot: dims 4sl..4sl+3
    int d0 = sl * 4;
    int gq = (blockIdx.x * 256 + threadIdx.x) >> 4;   // global quarter id
    int nq = (gridDim.x * 256) >> 4;
    const uint2* hhq = (const uint2*)hh;    // 16 uint2 per node row

    for (int v = gq; v < N_NODES; v += nq) {
        int rb = rowptr[v], re = rowptr[v + 1];
        float4 a0 = {0,0,0,0}, a1 = {0,0,0,0}, a2 = {0,0,0,0}, a3 = {0,0,0,0};
        int e = rb;
        for (; e + 4 <= re; e += 4) {
            unsigned p0 = ebuf[e + 0];
            unsigned p1 = ebuf[e + 1];
            unsigned p2 = ebuf[e + 2];
            unsigned p3 = ebuf[e + 3];
            uint2 g0 = hhq[(size_t)(p0 & 0xFFFFFu) * 16 + sl];
            uint2 g1 = hhq[(size_t)(p1 & 0xFFFFFu) * 16 + sl];
            uint2 g2 = hhq[(size_t)(p2 & 0xFFFFFu) * 16 + sl];
            uint2 g3 = hhq[(size_t)(p3 & 0xFFFFFu) * 16 + sl];
            const float* c0 = &bond_s[(p0 >> 20) * EMBED + d0];
            const float* c1 = &bond_s[(p1 >> 20) * EMBED + d0];
            const float* c2 = &bond_s[(p2 >> 20) * EMBED + d0];
            const float* c3 = &bond_s[(p3 >> 20) * EMBED + d0];
            float2 f0a = __half22float2(*(const __half2*)&g0.x);
            float2 f0b = __half22float2(*(const __half2*)&g0.y);
            float2 f1a = __half22float2(*(const __half2*)&g1.x);
            float2 f1b = __half22float2(*(const __half2*)&g1.y);
            float2 f2a = __half22float2(*(const __half2*)&g2.x);
            float2 f2b = __half22float2(*(const __half2*)&g2.y);
            float2 f3a = __half22float2(*(const __half2*)&g3.x);
            float2 f3b = __half22float2(*(const __half2*)&g3.y);
            a0.x += fmaxf(f0a.x + c0[0], 0.f); a0.y += fmaxf(f0a.y + c0[1], 0.f);
            a0.z += fmaxf(f0b.x + c0[2], 0.f); a0.w += fmaxf(f0b.y + c0[3], 0.f);
            a1.x += fmaxf(f1a.x + c1[0], 0.f); a1.y += fmaxf(f1a.y + c1[1], 0.f);
            a1.z += fmaxf(f1b.x + c1[2], 0.f); a1.w += fmaxf(f1b.y + c1[3], 0.f);
            a2.x += fmaxf(f2a.x + c2[0], 0.f); a2.y += fmaxf(f2a.y + c2[1], 0.f);
            a2.z += fmaxf(f2b.x + c2[2], 0.f); a2.w += fmaxf(f2b.y + c2[3], 0.f);
            a3.x += fmaxf(f3a.x + c3[0], 0.f); a3.y += fmaxf(f3a.y + c3[1], 0.f);
            a3.z += fmaxf(f3b.x + c3[2], 0.f); a3.w += fmaxf(f3b.y + c3[3], 0.f);
        }
        for (; e < re; ++e) {
            unsigned p = ebuf[e];
            uint2 g = hhq[(size_t)(p & 0xFFFFFu) * 16 + sl];
            const float* c = &bond_s[(p >> 20) * EMBED + d0];
            float2 fa = __half22float2(*(const __half2*)&g.x);
            float2 fb = __half22float2(*(const __half2*)&g.y);
            a0.x += fmaxf(fa.x + c[0], 0.f); a0.y += fmaxf(fa.y + c[1], 0.f);
            a0.z += fmaxf(fb.x + c[2], 0.f); a0.w += fmaxf(fb.y + c[3], 0.f);
        }
        float inv = 1.0f / fmaxf((float)(re - rb), 1.0f);
        float4 hr = ((const float4*)hmast)[(size_t)v * 16 + sl];
        float tx = (a0.x + a1.x + a2.x + a3.x) * inv + hr.x;
        float ty = (a0.y + a1.y + a2.y + a3.y) * inv + hr.y;
        float tz = (a0.z + a1.z + a2.z + a3.z) * inv + hr.z;
        float tw = (a0.w + a1.w + a2.w + a3.w) * inv + hr.w;
        __half2 m0 = __floats2half2_rn(tx, ty);
        __half2 m1 = __floats2half2_rn(tz, tw);
        uint2 packed;
        packed.x = *(unsigned*)&m0;
        packed.y = *(unsigned*)&m1;
        ((uint2*)t16)[(size_t)v * 16 + sl] = packed;
    }
}

// Fused GEMM + BN stats + grid barrier + BN/relu/residual (layers 0,1).
// MFMA accumulators stay in registers across the barrier: h_pre16 round-trip removed.
// C/D layout: col=lane&15, row=(lane>>4)*4+reg [m89].
__launch_bounds__(256, 2)
__global__ void gemm_bn_fused(const _Float16* __restrict__ t16,
                              const _Float16* __restrict__ wfrag,  // packed
                              const float* __restrict__ bias,
                              const float* __restrict__ gamma,
                              const float* __restrict__ beta,
                              float* __restrict__ colsum,
                              float* __restrict__ colsq,
                              int* __restrict__ bar,
                              float* __restrict__ h,      // fp32 master (in: residual, out: new h)
                              __half* __restrict__ hh) {  // fp16 mirror out
    __shared__ float red[4][8][16];
    __shared__ float sscale[EMBED];
    __shared__ float sshift[EMBED];

    int lane = threadIdx.x & 63;
    int wblk = threadIdx.x >> 6;
    int quad = lane >> 4;
    int col  = lane & 15;
    int wid  = blockIdx.x * 4 + wblk;

    half8 bf[4][2];
#pragma unroll
    for (int nt = 0; nt < 4; ++nt)
#pragma unroll
        for (int kh = 0; kh < 2; ++kh)
            bf[nt][kh] = *(const half8*)(wfrag + ((size_t)(nt * 2 + kh) * 64 + lane) * 8);

    float bj[4];
#pragma unroll
    for (int nt = 0; nt < 4; ++nt) bj[nt] = bias[nt * 16 + col];

    float lsum[4] = {0.f, 0.f, 0.f, 0.f};
    float lsq [4] = {0.f, 0.f, 0.f, 0.f};
    floatx4 c[TPW][4];

#pragma unroll
    for (int k = 0; k < TPW; ++k) {
        int tile = wid + k * GB_WAVES;
        if (tile >= NTILES) continue;
        int base = tile * 16;
        const _Float16* arow = t16 + (size_t)(base + col) * 64 + quad * 8;
        half8 a0 = *(const half8*)(arow);
        half8 a1 = *(const half8*)(arow + 32);
#pragma unroll
        for (int nt = 0; nt < 4; ++nt) {
            floatx4 cc = {bj[nt], bj[nt], bj[nt], bj[nt]};
            cc = __builtin_amdgcn_mfma_f32_16x16x32_f16(a0, bf[nt][0], cc, 0, 0, 0);
            cc = __builtin_amdgcn_mfma_f32_16x16x32_f16(a1, bf[nt][1], cc, 0, 0, 0);
            c[k][nt] = cc;
#pragma unroll
            for (int r = 0; r < 4; ++r) {
                float v = cc[r];
                lsum[nt] += v;
                lsq[nt]  += v * v;
            }
        }
    }

#pragma unroll
    for (int nt = 0; nt < 4; ++nt) {
        lsum[nt] += __shfl_xor(lsum[nt], 16); lsum[nt] += __shfl_xor(lsum[nt], 32);
        lsq[nt]  += __shfl_xor(lsq[nt], 16);  lsq[nt]  += __shfl_xor(lsq[nt], 32);
    }
    if (lane < 16) {
#pragma unroll
        for (int nt = 0; nt < 4; ++nt) {
            red[wblk][nt * 2 + 0][lane] = lsum[nt];
            red[wblk][nt * 2 + 1][lane] = lsq[nt];
        }
    }
    __syncthreads();
    if (threadIdx.x < 128) {
        int f = threadIdx.x >> 4, l = threadIdx.x & 15;
        float s = red[0][f][l] + red[1][f][l] + red[2][f][l] + red[3][f][l];
        int nt = f >> 1;
        if ((f & 1) == 0) atomicAdd(&colsum[nt * 16 + l], s);
        else              atomicAdd(&colsq[nt * 16 + l], s);
    }

    grid_barrier(bar);

    // stats -> scale/shift once per block (plain loads: L2-served broadcast, no herd)
    if (threadIdx.x < EMBED) {
        int j = threadIdx.x;
        const float invN = 1.0f / (float)N_NODES;
        float s = colsum[j];
        float q = colsq[j];
        float mu  = s * invN;
        float var = q * invN - mu * mu;
        float scv = rsqrtf(var + BN_EPS) * gamma[j];
        sscale[j] = scv;
        sshift[j] = beta[j] - mu * scv;
    }
    __syncthreads();

    float scr[4], shr[4];
#pragma unroll
    for (int nt = 0; nt < 4; ++nt) {
        scr[nt] = sscale[nt * 16 + col];
        shr[nt] = sshift[nt * 16 + col];
    }

#pragma unroll
    for (int k = 0; k < TPW; ++k) {
        int tile = wid + k * GB_WAVES;
        if (tile >= NTILES) continue;
        int base = tile * 16;
#pragma unroll
        for (int nt = 0; nt < 4; ++nt) {
#pragma unroll
            for (int r = 0; r < 4; ++r) {
                int node = base + quad * 4 + r;
                size_t off = (size_t)node * EMBED + nt * 16 + col;
                float y = fmaxf(c[k][nt][r] * scr[nt] + shr[nt], 0.0f);  // layers 0,1 relu
                float o = y + h[off];                                    // residual
                h[off] = o;
                hh[off] = __float2half(o);
            }
        }
    }
}

// Fused layer-2 GEMM + BN stats + barrier + BN/residual/graph-pool + barrier + pred.
// Final h never materialized. Pool exploits sorted graph_ids: tile-uniform graphs take
// one wave-reduced atomic per (nt,col); boundary tiles fall back to per-row atomics.
__launch_bounds__(256, 2)
__global__ void gemm_pool_fused(const _Float16* __restrict__ t16,
                                const _Float16* __restrict__ wfrag,
                                const float* __restrict__ bias,
                                const float* __restrict__ gamma,
                                const float* __restrict__ beta,
                                float* __restrict__ colsum,
                                float* __restrict__ colsq,
                                int* __restrict__ bar,       // two instances: bar, bar+BAR_STRIDE
                                const float* __restrict__ h, // residual (layer-1 output)
                                const int* __restrict__ gid,
                                const int* __restrict__ gstart,
                                float* __restrict__ gsum,    // [N_GRAPHS, EMBED] zeroed
                                const float* __restrict__ predW, // [64,128]
                                const float* __restrict__ predb, // [128]
                                float* __restrict__ out) {       // [G, OUT_DIM]
    __shared__ float red[4][8][16];
    __shared__ float sscale[EMBED];
    __shared__ float sshift[EMBED];
    __shared__ float gm[EMBED];

    int lane = threadIdx.x & 63;
    int wblk = threadIdx.x >> 6;
    int quad = lane >> 4;
    int col  = lane & 15;
    int wid  = blockIdx.x * 4 + wblk;

    half8 bf[4][2];
#pragma unroll
    for (int nt = 0; nt < 4; ++nt)
#pragma unroll
        for (int kh = 0; kh < 2; ++kh)
            bf[nt][kh] = *(const half8*)(wfrag + ((size_t)(nt * 2 + kh) * 64 + lane) * 8);

    float bj[4];
#pragma unroll
    for (int nt = 0; nt < 4; ++nt) bj[nt] = bias[nt * 16 + col];

    float lsum[4] = {0.f, 0.f, 0.f, 0.f};
    float lsq [4] = {0.f, 0.f, 0.f, 0.f};
    floatx4 c[TPW][4];

#pragma unroll
    for (int k = 0; k < TPW; ++k) {
        int tile = wid + k * GB_WAVES;
        if (tile >= NTILES) continue;
        int base = tile * 16;
        const _Float16* arow = t16 + (size_t)(base + col) * 64 + quad * 8;
        half8 a0 = *(const half8*)(arow);
        half8 a1 = *(const half8*)(arow + 32);
#pragma unroll
        for (int nt = 0; nt < 4; ++nt) {
            floatx4 cc = {bj[nt], bj[nt], bj[nt], bj[nt]};
            cc = __builtin_amdgcn_mfma_f32_16x16x32_f16(a0, bf[nt][0], cc, 0, 0, 0);
            cc = __builtin_amdgcn_mfma_f32_16x16x32_f16(a1, bf[nt][1], cc, 0, 0, 0);
            c[k][nt] = cc;
#pragma unroll
            for (int r = 0; r < 4; ++r) {
                float v = cc[r];
                lsum[nt] += v;
                lsq[nt]  += v * v;
            }
        }
    }

#pragma unroll
    for (int nt = 0; nt < 4; ++nt) {
        lsum[nt] += __shfl_xor(lsum[nt], 16); lsum[nt] += __shfl_xor(lsum[nt], 32);
        lsq[nt]  += __shfl_xor(lsq[nt], 16);  lsq[nt]  += __shfl_xor(lsq[nt], 32);
    }
    if (lane < 16) {
#pragma unroll
        for (int nt = 0; nt < 4; ++nt) {
            red[wblk][nt * 2 + 0][lane] = lsum[nt];
            red[wblk][nt * 2 + 1][lane] = lsq[nt];
        }
    }
    __syncthreads();
    if (threadIdx.x < 128) {
        int f = threadIdx.x >> 4, l = threadIdx.x & 15;
        float s = red[0][f][l] + red[1][f][l] + red[2][f][l] + red[3][f][l];
        int nt = f >> 1;
        if ((f & 1) == 0) atomicAdd(&colsum[nt * 16 + l], s);
        else              atomicAdd(&colsq[nt * 16 + l], s);
    }

    grid_barrier(bar);

    if (threadIdx.x < EMBED) {
        int j = threadIdx.x;
        const float invN = 1.0f / (float)N_NODES;
        float s = colsum[j];
        float q = colsq[j];
        float mu  = s * invN;
        float var = q * invN - mu * mu;
        float scv = rsqrtf(var + BN_EPS) * gamma[j];   // no relu on last layer
        sscale[j] = scv;
        sshift[j] = beta[j] - mu * scv;
    }
    __syncthreads();

    float scr[4], shr[4];
#pragma unroll
    for (int nt = 0; nt < 4; ++nt) {
        scr[nt] = sscale[nt * 16 + col];
        shr[nt] = sshift[nt * 16 + col];
    }

#pragma unroll
    for (int k = 0; k < TPW; ++k) {
        int tile = wid + k * GB_WAVES;
        if (tile >= NTILES) continue;
        int base = tile * 16;
        int g0  = gid[base];
        int g15 = gid[base + 15];
        float val[4][4];   // [nt][r]
#pragma unroll
        for (int r = 0; r < 4; ++r) {
            int node = base + quad * 4 + r;
#pragma unroll
            for (int nt = 0; nt < 4; ++nt) {
                size_t off = (size_t)node * EMBED + nt * 16 + col;
                val[nt][r] = c[k][nt][r] * scr[nt] + shr[nt] + h[off];
            }
        }
        if (g0 == g15) {   // gid sorted -> whole tile is one graph (wave-uniform branch)
#pragma unroll
            for (int nt = 0; nt < 4; ++nt) {
                float s = val[nt][0] + val[nt][1] + val[nt][2] + val[nt][3];
                s += __shfl_xor(s, 16);
                s += __shfl_xor(s, 32);
                if (quad == 0)
                    atomicAdd(&gsum[(size_t)g0 * EMBED + nt * 16 + col], s);
            }
        } else {
#pragma unroll
            for (int r = 0; r < 4; ++r) {
                int node = base + quad * 4 + r;
                int g = gid[node];
#pragma unroll
                for (int nt = 0; nt < 4; ++nt)
                    atomicAdd(&gsum[(size_t)g * EMBED + nt * 16 + col], val[nt][r]);
            }
        }
    }

    grid_barrier(bar + BAR_STRIDE);

    // pred: block per graph (grid-strided), gm row via LDS, 128 outputs
    for (int g = blockIdx.x; g < N_GRAPHS; g += gridDim.x) {
        int nb = gstart[g], ne = gstart[g + 1];
        float invc = 1.0f / fmaxf((float)(ne - nb), 1.0f);
        if (threadIdx.x < EMBED)
            gm[threadIdx.x] = gsum[(size_t)g * EMBED + threadIdx.x] * invc;
        __syncthreads();
        if (threadIdx.x < OUT_DIM) {
            float acc = predb[threadIdx.x];
#pragma unroll
            for (int d = 0; d < EMBED; ++d)
                acc += gm[d] * predW[d * OUT_DIM + threadIdx.x];
            out[g * OUT_DIM + threadIdx.x] = acc;
        }
        __syncthreads();
    }
}

// ---------------- launch ----------------

extern "C" void kernel_launch(void* const* d_in, const int* in_sizes, int n_in,
                              void* d_out, int out_size, void* d_ws, size_t ws_size,
                              hipStream_t stream) {
    const int*   nfeat      = (const int*)d_in[0];
    const int*   efeat      = (const int*)d_in[1];
    const int*   src        = (const int*)d_in[2];
    const int*   dst        = (const int*)d_in[3];
    const int*   gid        = (const int*)d_in[4];
    const float* atom_embed = (const float*)d_in[5];
    const float* bond_embed = (const float*)d_in[6];  // [3,5,64]
    const float* conv_W     = (const float*)d_in[7];  // [3,64,64]
    const float* conv_b     = (const float*)d_in[8];  // [3,64]
    const float* bn_gamma   = (const float*)d_in[9];  // [3,64]
    const float* bn_beta    = (const float*)d_in[10]; // [3,64]
    const float* pred_W     = (const float*)d_in[11]; // [64,128]
    const float* pred_b     = (const float*)d_in[12]; // [128]
    float* out = (float*)d_out;

    char* wsb = (char*)d_ws;
    float*     h        = (float*)wsb;                  wsb += (size_t)N_NODES * EMBED * 4;
    _Float16*  t16      = (_Float16*)wsb;               wsb += (size_t)N_NODES * EMBED * 2;
    __half*    hh       = (__half*)wsb;                 wsb += (size_t)N_NODES * EMBED * 2;
    _Float16*  wfrag    = (_Float16*)wsb;               wsb += (size_t)3 * 4096 * 2;
    unsigned*  binned   = (unsigned*)wsb;               wsb += (size_t)N_EDGES * 4;
    unsigned*  ebuf     = (unsigned*)wsb;               wsb += (size_t)N_EDGES * 4;
    int*       blockhist= (int*)wsb;                    wsb += (size_t)NBINS * NSCB * 4;
    int*       gofs     = (int*)wsb;                    wsb += (size_t)NBINS * NSCB * 4;
    int*       total    = (int*)wsb;                    wsb += (size_t)NBINS * 4;
    int*       binoff   = (int*)wsb;                    wsb += (size_t)(NBINS + 1) * 4;
    int*       rowptr   = (int*)wsb;                    wsb += (size_t)(N_NODES + 1) * 4;
    int*       gstart   = (int*)wsb;                    wsb += (size_t)(N_GRAPHS + 1) * 4;
    float*     colsum   = (float*)wsb;                  wsb += (size_t)3 * EMBED * 4;  // must stay
    float*     colsq    = (float*)wsb;                  wsb += (size_t)3 * EMBED * 4;  // adjacent
    float*     gsum     = (float*)wsb;                  wsb += (size_t)N_GRAPHS * EMBED * 4;
    int*       bar      = (int*)wsb;                    wsb += (size_t)4 * BAR_STRIDE * 4;

    embed_kernel<<<(N_NODES * 16 + 255) / 256, 256, 0, stream>>>(
        nfeat, atom_embed, (float4*)h, hh, gid, gstart, gsum);
    hist2_kernel<<<NSCB, 256, 0, stream>>>(dst, blockhist);
    binreduce_kernel<<<NBINS, NSCB, 0, stream>>>(blockhist, gofs, total);
    binscan_kernel<<<1, 1024, 0, stream>>>(total, binoff, colsum, bar, conv_W, wfrag);
    binscatter_kernel<<<NSCB, 256, 0, stream>>>(src, dst, efeat, binoff, gofs, binned);
    bincsr_kernel<<<NBINS, 256, 0, stream>>>(binned, binoff, rowptr, ebuf);

    for (int i = 0; i < 3; ++i) {
        gather_kernel<<<1536, 256, 0, stream>>>(
            rowptr, ebuf, bond_embed + i * 5 * EMBED, hh, h, (__half*)t16);
        const _Float16* wf = wfrag + (size_t)i * 4096;
        const float* bi = conv_b + (size_t)i * EMBED;
        const float* ga = bn_gamma + (size_t)i * EMBED;
        const float* be = bn_beta + (size_t)i * EMBED;
        float* cs = colsum + (size_t)i * EMBED;
        float* cq = colsq + (size_t)i * EMBED;
        if (i != 2) {
            gemm_bn_fused<<<GB_BLOCKS, 256, 0, stream>>>(
                t16, wf, bi, ga, be, cs, cq, bar + (size_t)i * BAR_STRIDE, h, hh);
        } else {
            gemm_pool_fused<<<GB_BLOCKS, 256, 0, stream>>>(
                t16, wf, bi, ga, be, cs, cq, bar + (size_t)2 * BAR_STRIDE,
                h, gid, gstart, gsum, pred_W, pred_b, out);
        }
    }
}

// Round 7
// 337.708 us; speedup vs baseline: 1.4707x; 1.0129x over previous
//
#include <hip/hip_runtime.h>
#include <hip/hip_fp16.h>

#define N_NODES 100000
#define N_EDGES 1000000
#define N_GRAPHS 1000
#define EMBED 64
#define OUT_DIM 128
#define BN_EPS 1e-5f
#define NBINS 782                          // dst>>7 -> 128 nodes per bin
#define NSCB 512                           // scatter blocks (fixed edge ranges)
#define EPB ((N_EDGES + NSCB - 1) / NSCB)  // 1954 edges per block
#define NTILES (N_NODES / 16)              // 6250 exact

#define GB_BLOCKS 512                      // fused gemm grid: 2 blocks/CU guaranteed resident
#define GB_WAVES (GB_BLOCKS * 4)           // 2048 waves
#define TPW 4                              // ceil(6250/2048) tiles per wave
#define BAR_STRIDE 8192                    // ints per barrier instance

typedef _Float16 half8 __attribute__((ext_vector_type(8)));
typedef float floatx4 __attribute__((ext_vector_type(4)));

// Software grid barrier v4 (graph-capture-safe). R6 verdict: barrier mechanics are NOT
// the remaining cost (v3==v4 within noise); kept as-is. Tree arrival (64 leaves x 8,
// 128B apart) + fan-out release flags; all RELAXED (happens-before via completed
// coherent-point RMWs; __syncthreads drains vmcnt before arrival [m97]).
__device__ __forceinline__ void grid_barrier(int* p) {
    __syncthreads();
    if (threadIdx.x == 0) {
        asm volatile("" ::: "memory");
        int leaf = (int)blockIdx.x >> 3;
        int old = __hip_atomic_fetch_add(p + leaf * 32, 1,
                                         __ATOMIC_RELAXED, __HIP_MEMORY_SCOPE_AGENT);
        if (old == 7) {
            int r = __hip_atomic_fetch_add(p + 2048, 1,
                                           __ATOMIC_RELAXED, __HIP_MEMORY_SCOPE_AGENT);
            if (r == 63) {
                for (int g = 0; g < 64; ++g)
                    __hip_atomic_store(p + 2080 + g * 32, 1,
                                       __ATOMIC_RELAXED, __HIP_MEMORY_SCOPE_AGENT);
            }
        }
        int spins = 0;
        while (__hip_atomic_load(p + 2080 + leaf * 32,
                                 __ATOMIC_RELAXED, __HIP_MEMORY_SCOPE_AGENT) == 0) {
            __builtin_amdgcn_s_sleep(8);
            if (++spins > (1 << 17)) break;   // ~25ms failsafe: fail visibly, never wedge
        }
        asm volatile("" ::: "memory");
    }
    __syncthreads();
}

// ---------------- one-time structure kernels ----------------

__global__ void embed_kernel(const int* __restrict__ nfeat,
                             const float* __restrict__ atom_embed,
                             float4* __restrict__ h4,
                             __half* __restrict__ hh,
                             const int* __restrict__ gid,
                             int* __restrict__ gstart,
                             float* __restrict__ gsum) {
    int idx = blockIdx.x * blockDim.x + threadIdx.x;   // one float4 each
    if (idx <= N_NODES) {   // folded gbound
        int cur  = (idx < N_NODES) ? gid[idx] : N_GRAPHS;
        int prev = (idx == 0) ? -1 : gid[idx - 1];
        for (int g = prev + 1; g <= cur; ++g) gstart[g] = idx;
    }
    if (idx < N_GRAPHS * EMBED) gsum[idx] = 0.0f;
    if (idx >= N_NODES * 16) return;
    int v = idx >> 4, q = idx & 15;
    const float4* ae = (const float4*)atom_embed;
    float4 val = ae[nfeat[v] * 16 + q];
    h4[idx] = val;
    __half2 m0 = __floats2half2_rn(val.x, val.y);
    __half2 m1 = __floats2half2_rn(val.z, val.w);
    uint2 packed;
    packed.x = *(unsigned*)&m0;
    packed.y = *(unsigned*)&m1;
    ((uint2*)hh)[idx] = packed;
}

__global__ void hist2_kernel(const int* __restrict__ dst, int* __restrict__ blockhist) {
    __shared__ int hist[NBINS];
    for (int i = threadIdx.x; i < NBINS; i += 256) hist[i] = 0;
    __syncthreads();
    int b = blockIdx.x;
    int e0 = b * EPB, e1 = min(e0 + EPB, N_EDGES);
    for (int e = e0 + threadIdx.x; e < e1; e += 256)
        atomicAdd(&hist[dst[e] >> 7], 1);
    __syncthreads();
    for (int i = threadIdx.x; i < NBINS; i += 256)
        blockhist[i * NSCB + b] = hist[i];
}

__global__ void binreduce_kernel(const int* __restrict__ blockhist,
                                 int* __restrict__ gofs, int* __restrict__ total) {
    __shared__ int sm[NSCB];
    int bin = blockIdx.x;
    int i = threadIdx.x;   // 0..511
    int orig = blockhist[bin * NSCB + i];
    sm[i] = orig;
    __syncthreads();
    for (int off = 1; off < NSCB; off <<= 1) {
        int val = sm[i];
        if (i >= off) val += sm[i - off];
        __syncthreads();
        sm[i] = val;
        __syncthreads();
    }
    gofs[bin * NSCB + i] = sm[i] - orig;   // exclusive within bin
    if (i == NSCB - 1) total[bin] = sm[i];
}

__global__ void binscan_kernel(const int* __restrict__ total,
                               int* __restrict__ binoff, float* __restrict__ stats,
                               int* __restrict__ bar,
                               const float* __restrict__ conv_W,
                               _Float16* __restrict__ wfrag) {
    __shared__ int sm[1024];
    int i = threadIdx.x;
    if (i < 6 * EMBED) stats[i] = 0.0f;
    for (int s = i; s < 4 * BAR_STRIDE; s += 1024) bar[s] = 0;   // 4 barrier instances
    // folded wpack: 3 layers x 512 slots
    for (int s = i; s < 3 * 512; s += 1024) {
        int L = s >> 9, slot = s & 511;
        int lane = slot & 63;
        int f = slot >> 6;          // nt*2+kh
        int nt = f >> 1, kh = f & 1;
        int n  = nt * 16 + (lane & 15);
        int k0 = kh * 32 + (lane >> 4) * 8;
        const float* W = conv_W + L * 4096;
        _Float16* out = wfrag + L * 4096;
#pragma unroll
        for (int j = 0; j < 8; ++j)
            out[slot * 8 + j] = (_Float16)W[(k0 + j) * 64 + n];
    }
    int orig = (i < NBINS) ? total[i] : 0;
    sm[i] = orig;
    __syncthreads();
    for (int off = 1; off < 1024; off <<= 1) {
        int val = sm[i];
        if (i >= off) val += sm[i - off];
        __syncthreads();
        sm[i] = val;
        __syncthreads();
    }
    if (i < NBINS) binoff[i] = sm[i] - orig;
    if (i == 0) binoff[NBINS] = N_EDGES;
}

__global__ void binscatter_kernel(const int* __restrict__ src, const int* __restrict__ dst,
                                  const int* __restrict__ efeat,
                                  const int* __restrict__ binoff, const int* __restrict__ gofs,
                                  unsigned* __restrict__ binned) {
    __shared__ int cur[NBINS];
    int b = blockIdx.x;
    for (int i = threadIdx.x; i < NBINS; i += 256)
        cur[i] = binoff[i] + gofs[i * NSCB + b];
    __syncthreads();
    int e0 = b * EPB, e1 = min(e0 + EPB, N_EDGES);
    for (int e = e0 + threadIdx.x; e < e1; e += 256) {
        int t = dst[e];
        int bin = t >> 7;
        int pos = atomicAdd(&cur[bin], 1);   // LDS atomic
        binned[pos] = (unsigned)src[e] | ((unsigned)efeat[e] << 17)
                    | ((unsigned)(t & 127) << 20);
    }
}

__global__ void bincsr_kernel(const unsigned* __restrict__ binned,
                              const int* __restrict__ binoff,
                              int* __restrict__ rowptr,
                              unsigned* __restrict__ ebuf) {
    __shared__ int cnt[128];
    __shared__ int sc[128];
    int b = blockIdx.x;
    int tid = threadIdx.x;
    int base = binoff[b], end = binoff[b + 1];

    if (tid < 128) cnt[tid] = 0;
    __syncthreads();

    for (int i = base + tid; i < end; i += 256)
        atomicAdd(&cnt[binned[i] >> 20], 1);
    __syncthreads();

    if (tid < 128) sc[tid] = cnt[tid];
    __syncthreads();
    for (int off = 1; off < 128; off <<= 1) {
        int val = 0;
        if (tid < 128) {
            val = sc[tid];
            if (tid >= off) val += sc[tid - off];
        }
        __syncthreads();
        if (tid < 128) sc[tid] = val;
        __syncthreads();
    }
    if (tid < 128) {
        int excl = sc[tid] - cnt[tid];
        int v = b * 128 + tid;
        if (v < N_NODES) rowptr[v] = base + excl;
        cnt[tid] = excl;   // becomes running cursor
    }
    if (b == 0 && tid == 255) rowptr[N_NODES] = N_EDGES;
    __syncthreads();

    for (int i = base + tid; i < end; i += 256) {
        unsigned rec = binned[i];
        int dl = rec >> 20;
        int pos = base + atomicAdd(&cnt[dl], 1);
        ebuf[pos] = (rec & 0x1FFFFu) | (((rec >> 17) & 0x7u) << 20);
    }
}

// ---------------- per-layer kernels ----------------

// Gather: quarter-wave per node. At the random-line service-rate wall (R6/R10/R18).
__launch_bounds__(256, 6)
__global__ void gather_kernel(const int* __restrict__ rowptr,
                              const unsigned* __restrict__ ebuf,
                              const float* __restrict__ bond,    // [5,64]
                              const __half* __restrict__ hh,     // fp16 mirror
                              const float* __restrict__ hmast,   // fp32 master
                              __half* __restrict__ t16) {
    __shared__ float bond_s[5 * EMBED];
    for (int i = threadIdx.x; i < 5 * EMBED; i += 256) bond_s[i] = bond[i];
    __syncthreads();

    int sl = threadIdx.x & 15;    // uint2 slot: dims 4sl..4sl+3
    int d0 = sl * 4;
    int gq = (blockIdx.x * 256 + threadIdx.x) >> 4;   // global quarter id
    int nq = (gridDim.x * 256) >> 4;
    const uint2* hhq = (const uint2*)hh;    // 16 uint2 per node row

    for (int v = gq; v < N_NODES; v += nq) {
        int rb = rowptr[v], re = rowptr[v + 1];
        float4 a0 = {0,0,0,0}, a1 = {0,0,0,0}, a2 = {0,0,0,0}, a3 = {0,0,0,0};
        int e = rb;
        for (; e + 4 <= re; e += 4) {
            unsigned p0 = ebuf[e + 0];
            unsigned p1 = ebuf[e + 1];
            unsigned p2 = ebuf[e + 2];
            unsigned p3 = ebuf[e + 3];
            uint2 g0 = hhq[(size_t)(p0 & 0xFFFFFu) * 16 + sl];
            uint2 g1 = hhq[(size_t)(p1 & 0xFFFFFu) * 16 + sl];
            uint2 g2 = hhq[(size_t)(p2 & 0xFFFFFu) * 16 + sl];
            uint2 g3 = hhq[(size_t)(p3 & 0xFFFFFu) * 16 + sl];
            const float* c0 = &bond_s[(p0 >> 20) * EMBED + d0];
            const float* c1 = &bond_s[(p1 >> 20) * EMBED + d0];
            const float* c2 = &bond_s[(p2 >> 20) * EMBED + d0];
            const float* c3 = &bond_s[(p3 >> 20) * EMBED + d0];
            float2 f0a = __half22float2(*(const __half2*)&g0.x);
            float2 f0b = __half22float2(*(const __half2*)&g0.y);
            float2 f1a = __half22float2(*(const __half2*)&g1.x);
            float2 f1b = __half22float2(*(const __half2*)&g1.y);
            float2 f2a = __half22float2(*(const __half2*)&g2.x);
            float2 f2b = __half22float2(*(const __half2*)&g2.y);
            float2 f3a = __half22float2(*(const __half2*)&g3.x);
            float2 f3b = __half22float2(*(const __half2*)&g3.y);
            a0.x += fmaxf(f0a.x + c0[0], 0.f); a0.y += fmaxf(f0a.y + c0[1], 0.f);
            a0.z += fmaxf(f0b.x + c0[2], 0.f); a0.w += fmaxf(f0b.y + c0[3], 0.f);
            a1.x += fmaxf(f1a.x + c1[0], 0.f); a1.y += fmaxf(f1a.y + c1[1], 0.f);
            a1.z += fmaxf(f1b.x + c1[2], 0.f); a1.w += fmaxf(f1b.y + c1[3], 0.f);
            a2.x += fmaxf(f2a.x + c2[0], 0.f); a2.y += fmaxf(f2a.y + c2[1], 0.f);
            a2.z += fmaxf(f2b.x + c2[2], 0.f); a2.w += fmaxf(f2b.y + c2[3], 0.f);
            a3.x += fmaxf(f3a.x + c3[0], 0.f); a3.y += fmaxf(f3a.y + c3[1], 0.f);
            a3.z += fmaxf(f3b.x + c3[2], 0.f); a3.w += fmaxf(f3b.y + c3[3], 0.f);
        }
        for (; e < re; ++e) {
            unsigned p = ebuf[e];
            uint2 g = hhq[(size_t)(p & 0xFFFFFu) * 16 + sl];
            const float* c = &bond_s[(p >> 20) * EMBED + d0];
            float2 fa = __half22float2(*(const __half2*)&g.x);
            float2 fb = __half22float2(*(const __half2*)&g.y);
            a0.x += fmaxf(fa.x + c[0], 0.f); a0.y += fmaxf(fa.y + c[1], 0.f);
            a0.z += fmaxf(fb.x + c[2], 0.f); a0.w += fmaxf(fb.y + c[3], 0.f);
        }
        float inv = 1.0f / fmaxf((float)(re - rb), 1.0f);
        float4 hr = ((const float4*)hmast)[(size_t)v * 16 + sl];
        float tx = (a0.x + a1.x + a2.x + a3.x) * inv + hr.x;
        float ty = (a0.y + a1.y + a2.y + a3.y) * inv + hr.y;
        float tz = (a0.z + a1.z + a2.z + a3.z) * inv + hr.z;
        float tw = (a0.w + a1.w + a2.w + a3.w) * inv + hr.w;
        __half2 m0 = __floats2half2_rn(tx, ty);
        __half2 m1 = __floats2half2_rn(tz, tw);
        uint2 packed;
        packed.x = *(unsigned*)&m0;
        packed.y = *(unsigned*)&m1;
        ((uint2*)t16)[(size_t)v * 16 + sl] = packed;
    }
}

// Fused GEMM + BN stats + grid barrier + BN/relu/residual (layers 0,1).
// R6 lesson: the fused epilogue had de-vectorized h/hh access (16 scalar RMWs/lane/tile,
// 10% HBM efficiency). Fix: per-wave LDS tile staging -> float4/uint2 streaming
// (1KB/instruction), scalar ops confined to LDS. DS ops within a wave are ordered:
// no extra barriers needed for the wave-private tile buffer.
__launch_bounds__(256, 2)
__global__ void gemm_bn_fused(const _Float16* __restrict__ t16,
                              const _Float16* __restrict__ wfrag,  // packed
                              const float* __restrict__ bias,
                              const float* __restrict__ gamma,
                              const float* __restrict__ beta,
                              float* __restrict__ colsum,
                              float* __restrict__ colsq,
                              int* __restrict__ bar,
                              float* __restrict__ h,      // fp32 master (in: residual, out: new h)
                              __half* __restrict__ hh) {  // fp16 mirror out
    __shared__ float red[4][8][16];
    __shared__ float sscale[EMBED];
    __shared__ float sshift[EMBED];
    __shared__ float4 tl[4][16][17];   // per-wave h-tile staging (pad 17 vs banks)

    int lane = threadIdx.x & 63;
    int wblk = threadIdx.x >> 6;
    int quad = lane >> 4;
    int col  = lane & 15;
    int wid  = blockIdx.x * 4 + wblk;

    half8 bf[4][2];
#pragma unroll
    for (int nt = 0; nt < 4; ++nt)
#pragma unroll
        for (int kh = 0; kh < 2; ++kh)
            bf[nt][kh] = *(const half8*)(wfrag + ((size_t)(nt * 2 + kh) * 64 + lane) * 8);

    float bj[4];
#pragma unroll
    for (int nt = 0; nt < 4; ++nt) bj[nt] = bias[nt * 16 + col];

    float lsum[4] = {0.f, 0.f, 0.f, 0.f};
    float lsq [4] = {0.f, 0.f, 0.f, 0.f};
    floatx4 c[TPW][4];

#pragma unroll
    for (int k = 0; k < TPW; ++k) {
        int tile = wid + k * GB_WAVES;
        if (tile >= NTILES) continue;
        int base = tile * 16;
        const _Float16* arow = t16 + (size_t)(base + col) * 64 + quad * 8;
        half8 a0 = *(const half8*)(arow);
        half8 a1 = *(const half8*)(arow + 32);
#pragma unroll
        for (int nt = 0; nt < 4; ++nt) {
            floatx4 cc = {bj[nt], bj[nt], bj[nt], bj[nt]};
            cc = __builtin_amdgcn_mfma_f32_16x16x32_f16(a0, bf[nt][0], cc, 0, 0, 0);
            cc = __builtin_amdgcn_mfma_f32_16x16x32_f16(a1, bf[nt][1], cc, 0, 0, 0);
            c[k][nt] = cc;
#pragma unroll
            for (int r = 0; r < 4; ++r) {
                float v = cc[r];
                lsum[nt] += v;
                lsq[nt]  += v * v;
            }
        }
    }

#pragma unroll
    for (int nt = 0; nt < 4; ++nt) {
        lsum[nt] += __shfl_xor(lsum[nt], 16); lsum[nt] += __shfl_xor(lsum[nt], 32);
        lsq[nt]  += __shfl_xor(lsq[nt], 16);  lsq[nt]  += __shfl_xor(lsq[nt], 32);
    }
    if (lane < 16) {
#pragma unroll
        for (int nt = 0; nt < 4; ++nt) {
            red[wblk][nt * 2 + 0][lane] = lsum[nt];
            red[wblk][nt * 2 + 1][lane] = lsq[nt];
        }
    }
    __syncthreads();
    if (threadIdx.x < 128) {
        int f = threadIdx.x >> 4, l = threadIdx.x & 15;
        float s = red[0][f][l] + red[1][f][l] + red[2][f][l] + red[3][f][l];
        int nt = f >> 1;
        if ((f & 1) == 0) atomicAdd(&colsum[nt * 16 + l], s);
        else              atomicAdd(&colsq[nt * 16 + l], s);
    }

    grid_barrier(bar);

    // stats -> scale/shift once per block (plain loads: L2-served broadcast)
    if (threadIdx.x < EMBED) {
        int j = threadIdx.x;
        const float invN = 1.0f / (float)N_NODES;
        float s = colsum[j];
        float q = colsq[j];
        float mu  = s * invN;
        float var = q * invN - mu * mu;
        float scv = rsqrtf(var + BN_EPS) * gamma[j];
        sscale[j] = scv;
        sshift[j] = beta[j] - mu * scv;
    }
    __syncthreads();

    float scr[4], shr[4];
#pragma unroll
    for (int nt = 0; nt < 4; ++nt) {
        scr[nt] = sscale[nt * 16 + col];
        shr[nt] = sshift[nt * 16 + col];
    }

    float4* h4g = (float4*)h;
    uint2*  hh2 = (uint2*)hh;
#pragma unroll
    for (int k = 0; k < TPW; ++k) {
        int tile = wid + k * GB_WAVES;
        if (tile >= NTILES) continue;
        size_t tb = (size_t)tile * 256;   // float4 index of tile start
        // A: vectorized h-tile load -> LDS
#pragma unroll
        for (int j = 0; j < 4; ++j)
            tl[wblk][lane >> 2][(lane & 3) * 4 + j] = h4g[tb + lane * 4 + j];
        // B: BN + relu + residual, in place in LDS (wave-ordered DS ops, no sync)
#pragma unroll
        for (int nt = 0; nt < 4; ++nt) {
            int f4 = nt * 4 + (col >> 2), cm = col & 3;
#pragma unroll
            for (int r = 0; r < 4; ++r) {
                int node = quad * 4 + r;
                float* slot = (float*)&tl[wblk][node][f4] + cm;
                float y = fmaxf(c[k][nt][r] * scr[nt] + shr[nt], 0.0f);  // layers 0,1 relu
                *slot = y + *slot;                                       // residual
            }
        }
        // C: vectorized store h + fp16 mirror
#pragma unroll
        for (int j = 0; j < 4; ++j) {
            float4 o = tl[wblk][lane >> 2][(lane & 3) * 4 + j];
            h4g[tb + lane * 4 + j] = o;
            __half2 m0 = __floats2half2_rn(o.x, o.y);
            __half2 m1 = __floats2half2_rn(o.z, o.w);
            uint2 pk;
            pk.x = *(unsigned*)&m0;
            pk.y = *(unsigned*)&m1;
            hh2[tb + lane * 4 + j] = pk;
        }
    }
}

// Fused layer-2 GEMM + BN stats + barrier + BN/residual/graph-pool + barrier + pred.
// h-residual reads staged per-wave through LDS (vectorized), same fix as bn.
__launch_bounds__(256, 2)
__global__ void gemm_pool_fused(const _Float16* __restrict__ t16,
                                const _Float16* __restrict__ wfrag,
                                const float* __restrict__ bias,
                                const float* __restrict__ gamma,
                                const float* __restrict__ beta,
                                float* __restrict__ colsum,
                                float* __restrict__ colsq,
                                int* __restrict__ bar,       // two instances: bar, bar+BAR_STRIDE
                                const float* __restrict__ h, // residual (layer-1 output)
                                const int* __restrict__ gid,
                                const int* __restrict__ gstart,
                                float* __restrict__ gsum,    // [N_GRAPHS, EMBED] zeroed
                                const float* __restrict__ predW, // [64,128]
                                const float* __restrict__ predb, // [128]
                                float* __restrict__ out) {       // [G, OUT_DIM]
    __shared__ float red[4][8][16];
    __shared__ float sscale[EMBED];
    __shared__ float sshift[EMBED];
    __shared__ float gm[EMBED];
    __shared__ float4 tl[4][16][17];   // per-wave h-tile staging

    int lane = threadIdx.x & 63;
    int wblk = threadIdx.x >> 6;
    int quad = lane >> 4;
    int col  = lane & 15;
    int wid  = blockIdx.x * 4 + wblk;

    half8 bf[4][2];
#pragma unroll
    for (int nt = 0; nt < 4; ++nt)
#pragma unroll
        for (int kh = 0; kh < 2; ++kh)
            bf[nt][kh] = *(const half8*)(wfrag + ((size_t)(nt * 2 + kh) * 64 + lane) * 8);

    float bj[4];
#pragma unroll
    for (int nt = 0; nt < 4; ++nt) bj[nt] = bias[nt * 16 + col];

    float lsum[4] = {0.f, 0.f, 0.f, 0.f};
    float lsq [4] = {0.f, 0.f, 0.f, 0.f};
    floatx4 c[TPW][4];

#pragma unroll
    for (int k = 0; k < TPW; ++k) {
        int tile = wid + k * GB_WAVES;
        if (tile >= NTILES) continue;
        int base = tile * 16;
        const _Float16* arow = t16 + (size_t)(base + col) * 64 + quad * 8;
        half8 a0 = *(const half8*)(arow);
        half8 a1 = *(const half8*)(arow + 32);
#pragma unroll
        for (int nt = 0; nt < 4; ++nt) {
            floatx4 cc = {bj[nt], bj[nt], bj[nt], bj[nt]};
            cc = __builtin_amdgcn_mfma_f32_16x16x32_f16(a0, bf[nt][0], cc, 0, 0, 0);
            cc = __builtin_amdgcn_mfma_f32_16x16x32_f16(a1, bf[nt][1], cc, 0, 0, 0);
            c[k][nt] = cc;
#pragma unroll
            for (int r = 0; r < 4; ++r) {
                float v = cc[r];
                lsum[nt] += v;
                lsq[nt]  += v * v;
            }
        }
    }

#pragma unroll
    for (int nt = 0; nt < 4; ++nt) {
        lsum[nt] += __shfl_xor(lsum[nt], 16); lsum[nt] += __shfl_xor(lsum[nt], 32);
        lsq[nt]  += __shfl_xor(lsq[nt], 16);  lsq[nt]  += __shfl_xor(lsq[nt], 32);
    }
    if (lane < 16) {
#pragma unroll
        for (int nt = 0; nt < 4; ++nt) {
            red[wblk][nt * 2 + 0][lane] = lsum[nt];
            red[wblk][nt * 2 + 1][lane] = lsq[nt];
        }
    }
    __syncthreads();
    if (threadIdx.x < 128) {
        int f = threadIdx.x >> 4, l = threadIdx.x & 15;
        float s = red[0][f][l] + red[1][f][l] + red[2][f][l] + red[3][f][l];
        int nt = f >> 1;
        if ((f & 1) == 0) atomicAdd(&colsum[nt * 16 + l], s);
        else              atomicAdd(&colsq[nt * 16 + l], s);
    }

    grid_barrier(bar);

    if (threadIdx.x < EMBED) {
        int j = threadIdx.x;
        const float invN = 1.0f / (float)N_NODES;
        float s = colsum[j];
        float q = colsq[j];
        float mu  = s * invN;
        float var = q * invN - mu * mu;
        float scv = rsqrtf(var + BN_EPS) * gamma[j];   // no relu on last layer
        sscale[j] = scv;
        sshift[j] = beta[j] - mu * scv;
    }
    __syncthreads();

    float scr[4], shr[4];
#pragma unroll
    for (int nt = 0; nt < 4; ++nt) {
        scr[nt] = sscale[nt * 16 + col];
        shr[nt] = sshift[nt * 16 + col];
    }

    const float4* h4g = (const float4*)h;
#pragma unroll
    for (int k = 0; k < TPW; ++k) {
        int tile = wid + k * GB_WAVES;
        if (tile >= NTILES) continue;
        int base = tile * 16;
        size_t tb = (size_t)tile * 256;
        // vectorized h-tile load -> LDS (wave-private, DS-ordered)
#pragma unroll
        for (int j = 0; j < 4; ++j)
            tl[wblk][lane >> 2][(lane & 3) * 4 + j] = h4g[tb + lane * 4 + j];

        int g0  = gid[base];
        int g15 = gid[base + 15];
        float val[4][4];   // [nt][r]
#pragma unroll
        for (int nt = 0; nt < 4; ++nt) {
            int f4 = nt * 4 + (col >> 2), cm = col & 3;
#pragma unroll
            for (int r = 0; r < 4; ++r) {
                int node = quad * 4 + r;
                float hval = ((const float*)&tl[wblk][node][f4])[cm];
                val[nt][r] = c[k][nt][r] * scr[nt] + shr[nt] + hval;
            }
        }
        if (g0 == g15) {   // gid sorted -> whole tile is one graph (wave-uniform branch)
#pragma unroll
            for (int nt = 0; nt < 4; ++nt) {
                float s = val[nt][0] + val[nt][1] + val[nt][2] + val[nt][3];
                s += __shfl_xor(s, 16);
                s += __shfl_xor(s, 32);
                if (quad == 0)
                    atomicAdd(&gsum[(size_t)g0 * EMBED + nt * 16 + col], s);
            }
        } else {
#pragma unroll
            for (int r = 0; r < 4; ++r) {
                int node = base + quad * 4 + r;
                int g = gid[node];
#pragma unroll
                for (int nt = 0; nt < 4; ++nt)
                    atomicAdd(&gsum[(size_t)g * EMBED + nt * 16 + col], val[nt][r]);
            }
        }
    }

    grid_barrier(bar + BAR_STRIDE);

    // pred: block per graph (grid-strided), gm row via LDS, 128 outputs
    for (int g = blockIdx.x; g < N_GRAPHS; g += gridDim.x) {
        int nb = gstart[g], ne = gstart[g + 1];
        float invc = 1.0f / fmaxf((float)(ne - nb), 1.0f);
        if (threadIdx.x < EMBED)
            gm[threadIdx.x] = gsum[(size_t)g * EMBED + threadIdx.x] * invc;
        __syncthreads();
        if (threadIdx.x < OUT_DIM) {
            float acc = predb[threadIdx.x];
#pragma unroll
            for (int d = 0; d < EMBED; ++d)
                acc += gm[d] * predW[d * OUT_DIM + threadIdx.x];
            out[g * OUT_DIM + threadIdx.x] = acc;
        }
        __syncthreads();
    }
}

// ---------------- launch ----------------

extern "C" void kernel_launch(void* const* d_in, const int* in_sizes, int n_in,
                              void* d_out, int out_size, void* d_ws, size_t ws_size,
                              hipStream_t stream) {
    const int*   nfeat      = (const int*)d_in[0];
    const int*   efeat      = (const int*)d_in[1];
    const int*   src        = (const int*)d_in[2];
    const int*   dst        = (const int*)d_in[3];
    const int*   gid        = (const int*)d_in[4];
    const float* atom_embed = (const float*)d_in[5];
    const float* bond_embed = (const float*)d_in[6];  // [3,5,64]
    const float* conv_W     = (const float*)d_in[7];  // [3,64,64]
    const float* conv_b     = (const float*)d_in[8];  // [3,64]
    const float* bn_gamma   = (const float*)d_in[9];  // [3,64]
    const float* bn_beta    = (const float*)d_in[10]; // [3,64]
    const float* pred_W     = (const float*)d_in[11]; // [64,128]
    const float* pred_b     = (const float*)d_in[12]; // [128]
    float* out = (float*)d_out;

    char* wsb = (char*)d_ws;
    float*     h        = (float*)wsb;                  wsb += (size_t)N_NODES * EMBED * 4;
    _Float16*  t16      = (_Float16*)wsb;               wsb += (size_t)N_NODES * EMBED * 2;
    __half*    hh       = (__half*)wsb;                 wsb += (size_t)N_NODES * EMBED * 2;
    _Float16*  wfrag    = (_Float16*)wsb;               wsb += (size_t)3 * 4096 * 2;
    unsigned*  binned   = (unsigned*)wsb;               wsb += (size_t)N_EDGES * 4;
    unsigned*  ebuf     = (unsigned*)wsb;               wsb += (size_t)N_EDGES * 4;
    int*       blockhist= (int*)wsb;                    wsb += (size_t)NBINS * NSCB * 4;
    int*       gofs     = (int*)wsb;                    wsb += (size_t)NBINS * NSCB * 4;
    int*       total    = (int*)wsb;                    wsb += (size_t)NBINS * 4;
    int*       binoff   = (int*)wsb;                    wsb += (size_t)(NBINS + 1) * 4;
    int*       rowptr   = (int*)wsb;                    wsb += (size_t)(N_NODES + 1) * 4;
    int*       gstart   = (int*)wsb;                    wsb += (size_t)(N_GRAPHS + 1) * 4;
    float*     colsum   = (float*)wsb;                  wsb += (size_t)3 * EMBED * 4;  // must stay
    float*     colsq    = (float*)wsb;                  wsb += (size_t)3 * EMBED * 4;  // adjacent
    float*     gsum     = (float*)wsb;                  wsb += (size_t)N_GRAPHS * EMBED * 4;
    int*       bar      = (int*)wsb;                    wsb += (size_t)4 * BAR_STRIDE * 4;

    embed_kernel<<<(N_NODES * 16 + 255) / 256, 256, 0, stream>>>(
        nfeat, atom_embed, (float4*)h, hh, gid, gstart, gsum);
    hist2_kernel<<<NSCB, 256, 0, stream>>>(dst, blockhist);
    binreduce_kernel<<<NBINS, NSCB, 0, stream>>>(blockhist, gofs, total);
    binscan_kernel<<<1, 1024, 0, stream>>>(total, binoff, colsum, bar, conv_W, wfrag);
    binscatter_kernel<<<NSCB, 256, 0, stream>>>(src, dst, efeat, binoff, gofs, binned);
    bincsr_kernel<<<NBINS, 256, 0, stream>>>(binned, binoff, rowptr, ebuf);

    for (int i = 0; i < 3; ++i) {
        gather_kernel<<<1536, 256, 0, stream>>>(
            rowptr, ebuf, bond_embed + i * 5 * EMBED, hh, h, (__half*)t16);
        const _Float16* wf = wfrag + (size_t)i * 4096;
        const float* bi = conv_b + (size_t)i * EMBED;
        const float* ga = bn_gamma + (size_t)i * EMBED;
        const float* be = bn_beta + (size_t)i * EMBED;
        float* cs = colsum + (size_t)i * EMBED;
        float* cq = colsq + (size_t)i * EMBED;
        if (i != 2) {
            gemm_bn_fused<<<GB_BLOCKS, 256, 0, stream>>>(
                t16, wf, bi, ga, be, cs, cq, bar + (size_t)i * BAR_STRIDE, h, hh);
        } else {
            gemm_pool_fused<<<GB_BLOCKS, 256, 0, stream>>>(
                t16, wf, bi, ga, be, cs, cq, bar + (size_t)2 * BAR_STRIDE,
                h, gid, gstart, gsum, pred_W, pred_b, out);
        }
    }
}